// Round 6
// baseline (1026.439 us; speedup 1.0000x reference)
//
#include <hip/hip_runtime.h>
#include <math.h>

constexpr int NTOT = 65536;
constexpr int D    = 128;
constexpr int BG   = 256;
constexpr int E0 = 131072, E1 = 104960, E2 = 83968;
constexpr int EG0 = 512;
constexpr int KP0 = 410, KP1 = 328;

// ---------- embeddings ----------
__global__ __launch_bounds__(256) void k_embed_x(const int* __restrict__ xi,
                                                 const float* __restrict__ tab,
                                                 float* __restrict__ x) {
  int t = blockIdx.x * 256 + threadIdx.x;      // NTOT*32 threads
  int v = t >> 5, q = (t & 31) << 2;
  float4 s = {0.f, 0.f, 0.f, 0.f};
#pragma unroll
  for (int j = 0; j < 9; ++j) {
    int r = xi[v * 9 + j];
    float4 a = *(const float4*)&tab[r * D + q];
    s.x += a.x; s.y += a.y; s.z += a.z; s.w += a.w;
  }
  *(float4*)&x[v * D + q] = s;
}

__global__ __launch_bounds__(256) void k_embed_e(const int* __restrict__ bi,
                                                 const float* __restrict__ tab,
                                                 float* __restrict__ e) {
  int t = blockIdx.x * 256 + threadIdx.x;      // E0*32 threads
  int i = t >> 5, q = (t & 31) << 2;
  float4 s = {0.f, 0.f, 0.f, 0.f};
#pragma unroll
  for (int j = 0; j < 3; ++j) {
    int r = bi[i * 3 + j];
    float4 a = *(const float4*)&tab[r * D + q];
    s.x += a.x; s.y += a.y; s.z += a.z; s.w += a.w;
  }
  *(float4*)&e[i * D + q] = s;
}

// ---------- GEMM: C[M][128] = A[M][128] @ W[128][128] (+bias) ----------
__global__ __launch_bounds__(256) void k_gemm128(const float* __restrict__ A,
                                                 const float* __restrict__ W,
                                                 const float* __restrict__ bias,
                                                 float* __restrict__ C) {
  __shared__ float As[64][36];
  __shared__ float Ws[32][132];
  const int t  = threadIdx.x;
  const int m0 = blockIdx.x * 64;
  const int rg = t >> 4, cg = t & 15;
  const int c0 = cg * 4, c1 = 64 + cg * 4;
  float acc[4][8] = {};
  for (int k0 = 0; k0 < 128; k0 += 32) {
    for (int q = t; q < 512; q += 256) {           // A tile 64x32
      int r = q >> 3, cc = (q & 7) << 2;
      *(float4*)&As[r][cc] = *(const float4*)&A[(m0 + r) * 128 + k0 + cc];
    }
    for (int q = t; q < 1024; q += 256) {          // W tile 32x128
      int r = q >> 5, cc = (q & 31) << 2;
      *(float4*)&Ws[r][cc] = *(const float4*)&W[(k0 + r) * 128 + cc];
    }
    __syncthreads();
#pragma unroll 8
    for (int k = 0; k < 32; ++k) {
      float a[4] = {As[rg * 4 + 0][k], As[rg * 4 + 1][k],
                    As[rg * 4 + 2][k], As[rg * 4 + 3][k]};
      float4 w0 = *(float4*)&Ws[k][c0];
      float4 w1 = *(float4*)&Ws[k][c1];
#pragma unroll
      for (int i2 = 0; i2 < 4; ++i2) {
        acc[i2][0] += a[i2] * w0.x; acc[i2][1] += a[i2] * w0.y;
        acc[i2][2] += a[i2] * w0.z; acc[i2][3] += a[i2] * w0.w;
        acc[i2][4] += a[i2] * w1.x; acc[i2][5] += a[i2] * w1.y;
        acc[i2][6] += a[i2] * w1.z; acc[i2][7] += a[i2] * w1.w;
      }
    }
    __syncthreads();
  }
  float4 b0 = {0.f,0.f,0.f,0.f}, b1 = {0.f,0.f,0.f,0.f};
  if (bias) { b0 = *(const float4*)&bias[c0]; b1 = *(const float4*)&bias[c1]; }
#pragma unroll
  for (int i2 = 0; i2 < 4; ++i2) {
    int r = m0 + rg * 4 + i2;
    float4 o0 = {acc[i2][0]+b0.x, acc[i2][1]+b0.y, acc[i2][2]+b0.z, acc[i2][3]+b0.w};
    float4 o1 = {acc[i2][4]+b1.x, acc[i2][5]+b1.y, acc[i2][6]+b1.z, acc[i2][7]+b1.w};
    *(float4*)&C[r * 128 + c0] = o0;
    *(float4*)&C[r * 128 + c1] = o1;
  }
}

// ---------- fused GCN layer, split by column half: 2 blocks per graph. ----------
template <int EG, bool HAS_EW>
__global__ __launch_bounds__(1024, 8) void k_gcn_fused(const int* __restrict__ ei, int E,
                                                       const float* __restrict__ e,
                                                       const float* __restrict__ h,
                                                       const float* __restrict__ ew,
                                                       const float* __restrict__ root,
                                                       float* __restrict__ x,
                                                       float* __restrict__ xs) {
  constexpr int NE = (EG + 15) / 16;   // edges per wave (max)
  constexpr int CH = 8;                // load-batch chunk
  __shared__ float acc[256 * 64];      // 64 KB (this half's columns)
  __shared__ float degs[256];
  __shared__ int   pke[EG];
  __shared__ float redm[1024], reds[1024];
  const int bid = blockIdx.x;
  const int g = bid >> 1, half = bid & 1;
  const int t = threadIdx.x, wid = t >> 6, lane = t & 63;
  const int col = half * 64 + lane;

  float4* a4 = (float4*)acc;
  float4 z4 = {0.f, 0.f, 0.f, 0.f};
  for (int i = t; i < 4096; i += 1024) a4[i] = z4;
  if (t < 256) degs[t] = 0.f;
  __syncthreads();

  // stage packed indices in LDS + degree count (src only)
  for (int j = t; j < EG; j += 1024) {
    int s = ei[g * EG + j] & 255, d = ei[E + g * EG + j] & 255;
    pke[j] = s | (d << 8);
    atomicAdd(&degs[s], 1.f);
  }
  __syncthreads();

  // chunked scatter: batch-issue loads, then compute + ds_add
  for (int c0 = 0; c0 < NE; c0 += CH) {
    int pp[CH]; float ea[CH], ha[CH], wv[CH];
#pragma unroll
    for (int u = 0; u < CH; ++u) {
      int j = wid + (c0 + u) * 16;
      pp[u] = (c0 + u < NE && j < EG) ? pke[j] : -1;
      if (pp[u] >= 0) {
        int idx = g * EG + j;
        ea[u] = e[(size_t)idx * 128 + col];
        ha[u] = h[(size_t)(g * 256 + (pp[u] & 255)) * 128 + col];
        if (HAS_EW) wv[u] = ew[idx];
      }
    }
#pragma unroll
    for (int u = 0; u < CH; ++u) {
      if (pp[u] >= 0) {
        int s = pp[u] & 255, d = (pp[u] >> 8) & 255;
        float coef = rsqrtf((degs[s] + 1.f) * (degs[d] + 1.f));
        if (HAS_EW) coef *= wv[u];
        atomicAdd(&acc[d * 64 + lane], coef * fmaxf(ha[u] + ea[u], 0.f));
      }
    }
  }
  __syncthreads();

  // finalize: x = relu(acc + relu(h+root)/deg); keep in LDS for readout
  for (int i = t; i < 16384; i += 1024) {
    int n = i >> 6, c = i & 63;
    float inv = 1.f / (degs[n] + 1.f);
    size_t gi = (size_t)(g * 256 + n) * 128 + half * 64 + c;
    float xv = fmaxf(acc[i] + fmaxf(h[gi] + root[half * 64 + c], 0.f) * inv, 0.f);
    x[gi] = xv;
    acc[i] = xv;
  }
  __syncthreads();

  // readout: 16 partials per column
  {
    int c = t & 63, r = t >> 6;
    float mx = -1e30f, sm = 0.f;
    for (int n = r; n < 256; n += 16) {
      float v = acc[n * 64 + c];
      mx = fmaxf(mx, v); sm += v;
    }
    redm[t] = mx; reds[t] = sm;
  }
  __syncthreads();
  if (t < 64) {
    float M = redm[t], S2 = reds[t];
#pragma unroll
    for (int k = 1; k < 16; ++k) {
      M = fmaxf(M, redm[k * 64 + t]);
      S2 += reds[k * 64 + t];
    }
    int cc = half * 64 + t;
    xs[g * 384 + cc]       += M;
    xs[g * 384 + 128 + cc] += S2 * (1.f / 256.f);
    xs[g * 384 + 256 + cc] += S2;
  }
}

// ---------- fused hyperconv (no score work): scatter + gather + eout.
//            Split by column half: 2 blocks per graph. ----------
template <int EG>
__global__ __launch_bounds__(1024, 8) void k_hyper_fused(const int* __restrict__ ei, int E,
                                                         const float* __restrict__ z,
                                                         const float* __restrict__ bias,
                                                         float* __restrict__ eout) {
  constexpr int NE = (EG + 15) / 16;
  constexpr int CH = 8;
  __shared__ float S[256 * 64];        // 64 KB
  __shared__ float bcs[256];
  __shared__ int   pke[EG];
  const int bid = blockIdx.x;
  const int g = bid >> 1, half = bid & 1;
  const int t = threadIdx.x, wid = t >> 6, lane = t & 63;
  const int col = half * 64 + lane;

  float4* s4 = (float4*)S;
  float4 z4 = {0.f, 0.f, 0.f, 0.f};
  for (int i = t; i < 4096; i += 1024) s4[i] = z4;
  if (t < 256) bcs[t] = 0.f;
  __syncthreads();

  // stage indices + bc counts
  for (int j = t; j < EG; j += 1024) {
    int s = ei[g * EG + j] & 255, d = ei[E + g * EG + j] & 255;
    pke[j] = s | (d << 8);
    atomicAdd(&bcs[s], 1.f);
    atomicAdd(&bcs[d], 1.f);
  }
  __syncthreads();

  // scatter S += z (both endpoints), chunked batched loads
  for (int c0 = 0; c0 < NE; c0 += CH) {
    int pp[CH]; float zv[CH];
#pragma unroll
    for (int u = 0; u < CH; ++u) {
      int j = wid + (c0 + u) * 16;
      pp[u] = (c0 + u < NE && j < EG) ? pke[j] : -1;
      if (pp[u] >= 0) zv[u] = z[(size_t)(g * EG + j) * 128 + col];
    }
#pragma unroll
    for (int u = 0; u < CH; ++u) {
      if (pp[u] >= 0) {
        atomicAdd(&S[(pp[u] & 255) * 64 + lane], zv[u]);
        atomicAdd(&S[((pp[u] >> 8) & 255) * 64 + lane], zv[u]);
      }
    }
  }
  __syncthreads();

  // gather + eout write (no shuffles, no global atomics)
  const float bv0 = bias[col];
  for (int c0 = 0; c0 < NE; c0 += CH) {
    int pp[CH]; float zv[CH];
#pragma unroll
    for (int u = 0; u < CH; ++u) {
      int j = wid + (c0 + u) * 16;
      pp[u] = (c0 + u < NE && j < EG) ? pke[j] : -1;
      if (pp[u] >= 0) zv[u] = z[(size_t)(g * EG + j) * 128 + col];
    }
#pragma unroll
    for (int u = 0; u < CH; ++u) {
      if (pp[u] >= 0) {
        int j = wid + (c0 + u) * 16;
        int s = pp[u] & 255, d = (pp[u] >> 8) & 255;
        float bs = bcs[s], bd = bcs[d];
        float bis  = (bs != 1.0f) ? 1.f / bs : 0.f;
        float bid_ = (bd != 1.0f) ? 1.f / bd : 0.f;
        float dinv = 1.f / (1.f + (bs != 1.f ? 1.f : 0.f) + (bd != 1.f ? 1.f : 0.f));
        float o0 = fmaxf(dinv * (S[s * 64 + lane] * bis + S[d * 64 + lane] * bid_ + zv[u]) + bv0, 0.f);
        eout[(size_t)(g * EG + j) * 128 + col] = o0;
      }
    }
  }
}

// ---------- per-graph: score dot + scalar hyperconv + tanh + top-k sort + compaction ----------
template <int EG, int KEEP, int ENEW>
__global__ __launch_bounds__(256) void k_sortcompact(const int* __restrict__ ei_old, int E_old,
                                                     const float* __restrict__ wsc,
                                                     const float* __restrict__ bsc,
                                                     const float* __restrict__ e_old,
                                                     int* __restrict__ ei_new,
                                                     float* __restrict__ e_new,
                                                     float* __restrict__ ew) {
  __shared__ float ss[512];
  __shared__ int   si[512];
  __shared__ int   pke[512];
  __shared__ float zsh[512];
  __shared__ float wl[128];
  __shared__ float Ssh[256], bcs[256];
  int g = blockIdx.x, t = threadIdx.x;
  const int wv = t >> 6, ln = t & 63;
  if (t < 256) { Ssh[t] = 0.f; bcs[t] = 0.f; }
  if (t < 128) wl[t] = wsc[t];
  __syncthreads();
  for (int j = t; j < EG; j += 256) {
    int s = ei_old[g * EG + j] & 255, d = ei_old[E_old + g * EG + j] & 255;
    pke[j] = s | (d << 8);
    atomicAdd(&bcs[s], 1.f);
    atomicAdd(&bcs[d], 1.f);
  }
  __syncthreads();
  // score dot: zsh[j] = e_old[j] . wsc  (4 waves, coalesced row reads)
  {
    const float w0 = wl[ln], w1 = wl[ln + 64];
    for (int j = wv; j < EG; j += 4) {
      const float* ep = e_old + (size_t)(g * EG + j) * 128;
      float p = ep[ln] * w0 + ep[ln + 64] * w1;
#pragma unroll
      for (int off = 32; off > 0; off >>= 1) p += __shfl_xor(p, off);
      if (ln == 0) zsh[j] = p;
    }
  }
  __syncthreads();
  for (int j = t; j < EG; j += 256) {
    float v = zsh[j];
    atomicAdd(&Ssh[pke[j] & 255], v);
    atomicAdd(&Ssh[(pke[j] >> 8) & 255], v);
  }
  __syncthreads();
  float bsc0 = bsc[0];
  for (int i = t; i < 512; i += 256) {
    if (i < EG) {
      int s = pke[i] & 255, d = (pke[i] >> 8) & 255;
      float bs = bcs[s], bd = bcs[d];
      float bis  = (bs != 1.f) ? 1.f / bs : 0.f;
      float bid_ = (bd != 1.f) ? 1.f / bd : 0.f;
      float dn = 1.f + (bs != 1.f ? 1.f : 0.f) + (bd != 1.f ? 1.f : 0.f);
      ss[i] = tanhf((Ssh[s] * bis + Ssh[d] * bid_ + zsh[i]) / dn + bsc0);
      si[i] = i;
    } else { ss[i] = -INFINITY; si[i] = 0x7FFFFFFF; }
  }
  __syncthreads();
  for (int k = 2; k <= 512; k <<= 1) {
    for (int j = k >> 1; j > 0; j >>= 1) {
      for (int i = t; i < 512; i += 256) {
        int ixj = i ^ j;
        if (ixj > i) {
          float s1 = ss[i], s2 = ss[ixj];
          int i1 = si[i], i2 = si[ixj];
          bool firstBetter = (s1 > s2) || (s1 == s2 && i1 < i2);
          bool desc = ((i & k) == 0);
          if (desc != firstBetter) {
            ss[i] = s2; si[i] = i2; ss[ixj] = s1; si[ixj] = i1;
          }
        }
      }
      __syncthreads();
    }
  }
  for (int j = t; j < KEEP; j += 256) {
    int oldp = g * EG + si[j];
    int newp = g * KEEP + j;
    ei_new[newp]        = ei_old[oldp];
    ei_new[ENEW + newp] = ei_old[E_old + oldp];
    ew[newp] = fminf(fmaxf(ss[j], 0.f), 1.f);
  }
  __syncthreads();
  for (int q = t; q < KEEP * 32; q += 256) {
    int j = q >> 5, c4 = (q & 31) << 2;
    *(float4*)&e_new[(size_t)(g * KEEP + j) * 128 + c4] =
        *(const float4*)&e_old[(size_t)(g * EG + si[j]) * 128 + c4];
  }
}

// ---------- final MLP ----------
__global__ __launch_bounds__(128) void k_mlp(const float* __restrict__ xs,
                                             const float* __restrict__ Wc1, const float* __restrict__ bc1,
                                             const float* __restrict__ Wc2, const float* __restrict__ bc2,
                                             const float* __restrict__ Wc3, const float* __restrict__ bc3,
                                             float* __restrict__ out) {
  __shared__ float row[384];
  __shared__ float h1[128];
  __shared__ float h2[64];
  int g = blockIdx.x, t = threadIdx.x;
  for (int i = t; i < 384; i += 128) row[i] = xs[g * 384 + i];
  __syncthreads();
  float a = bc1[t];
  for (int k = 0; k < 384; ++k) a += row[k] * Wc1[k * 128 + t];
  h1[t] = fmaxf(a, 0.f);
  __syncthreads();
  if (t < 64) {
    float b = bc2[t];
    for (int k = 0; k < 128; ++k) b += h1[k] * Wc2[k * 64 + t];
    h2[t] = fmaxf(b, 0.f);
  }
  __syncthreads();
  float o = bc3[t];
  for (int k = 0; k < 64; ++k) o += h2[k] * Wc3[k * 128 + t];
  out[g * 128 + t] = o;
}

extern "C" void kernel_launch(void* const* d_in, const int* in_sizes, int n_in,
                              void* d_out, int out_size, void* d_ws, size_t ws_size,
                              hipStream_t stream) {
  (void)in_sizes; (void)n_in; (void)out_size; (void)ws_size;
  const int*   x_idx  = (const int*)d_in[0];
  const int*   b_idx  = (const int*)d_in[1];
  const int*   ei0    = (const int*)d_in[2];
  const float* atom_t = (const float*)d_in[4];
  const float* bond_t = (const float*)d_in[5];
  const float* W_gcn  = (const float*)d_in[6];
  const float* b_gcn  = (const float*)d_in[7];
  const float* root   = (const float*)d_in[8];
  const float* W_hyp  = (const float*)d_in[9];
  const float* b_hyp  = (const float*)d_in[10];
  const float* W_sc   = (const float*)d_in[11];
  const float* b_sc   = (const float*)d_in[12];
  const float* Wc1    = (const float*)d_in[13];
  const float* bc1_   = (const float*)d_in[14];
  const float* Wc2    = (const float*)d_in[15];
  const float* bc2_   = (const float*)d_in[16];
  const float* Wc3    = (const float*)d_in[17];
  const float* bc3_   = (const float*)d_in[18];
  float* out = (float*)d_out;

  // workspace layout
  float* x    = (float*)d_ws;
  float* h    = x    + (size_t)NTOT * D;
  float* eA   = h    + (size_t)NTOT * D;
  float* eB   = eA   + (size_t)E0 * D;
  float* ew   = eB   + (size_t)E0 * D;
  float* xs   = ew   + E0;
  int*   eiB  = (int*)(xs + BG * 384);
  int*   eiA2 = eiB + 2 * E0;

  hipMemsetAsync(xs, 0, BG * 384 * 4, stream);
  k_embed_x<<<NTOT * 32 / 256, 256, 0, stream>>>(x_idx, atom_t, x);
  k_embed_e<<<E0 * 32 / 256, 256, 0, stream>>>(b_idx, bond_t, eA);

  // ---- layer 0 ----
  k_gemm128<<<NTOT / 64, 256, 0, stream>>>(x, W_gcn, b_gcn, h);
  k_gcn_fused<EG0, false><<<2 * BG, 1024, 0, stream>>>(ei0, E0, eA, h, nullptr, root, x, xs);
  k_gemm128<<<E0 / 64, 256, 0, stream>>>(eA, W_hyp, nullptr, eB);
  k_hyper_fused<EG0><<<2 * BG, 1024, 0, stream>>>(ei0, E0, eB, b_hyp, eA);
  k_sortcompact<EG0, KP0, E1><<<BG, 256, 0, stream>>>(ei0, E0, W_sc, b_sc, eA, eiB, eB, ew);

  // ---- layer 1 ----
  k_gemm128<<<NTOT / 64, 256, 0, stream>>>(x, W_gcn + D * D, b_gcn + D, h);
  k_gcn_fused<KP0, true><<<2 * BG, 1024, 0, stream>>>(eiB, E1, eB, h, ew, root + D, x, xs);
  k_gemm128<<<E1 / 64, 256, 0, stream>>>(eB, W_hyp + D * D, nullptr, eA);
  k_hyper_fused<KP0><<<2 * BG, 1024, 0, stream>>>(eiB, E1, eA, b_hyp + D, eB);
  k_sortcompact<KP0, KP1, E2><<<BG, 256, 0, stream>>>(eiB, E1, W_sc + D, b_sc + 1, eB, eiA2, eA, ew);

  // ---- layer 2 ----
  k_gemm128<<<NTOT / 64, 256, 0, stream>>>(x, W_gcn + 2 * D * D, b_gcn + 2 * D, h);
  k_gcn_fused<KP1, true><<<2 * BG, 1024, 0, stream>>>(eiA2, E2, eA, h, ew, root + 2 * D, x, xs);

  k_mlp<<<BG, 128, 0, stream>>>(xs, Wc1, bc1_, Wc2, bc2_, Wc3, bc3_, out);
}

// Round 7
// 933.020 us; speedup vs baseline: 1.1001x; 1.1001x over previous
//
#include <hip/hip_runtime.h>
#include <math.h>

constexpr int NTOT = 65536;
constexpr int D    = 128;
constexpr int BG   = 256;
constexpr int E0 = 131072, E1 = 104960, E2 = 83968;
constexpr int EG0 = 512;
constexpr int KP0 = 410, KP1 = 328;

// ---------- embeddings ----------
__global__ __launch_bounds__(256) void k_embed_x(const int* __restrict__ xi,
                                                 const float* __restrict__ tab,
                                                 float* __restrict__ x) {
  int t = blockIdx.x * 256 + threadIdx.x;      // NTOT*32 threads
  int v = t >> 5, q = (t & 31) << 2;
  float4 s = {0.f, 0.f, 0.f, 0.f};
#pragma unroll
  for (int j = 0; j < 9; ++j) {
    int r = xi[v * 9 + j];
    float4 a = *(const float4*)&tab[r * D + q];
    s.x += a.x; s.y += a.y; s.z += a.z; s.w += a.w;
  }
  *(float4*)&x[v * D + q] = s;
}

__global__ __launch_bounds__(256) void k_embed_e(const int* __restrict__ bi,
                                                 const float* __restrict__ tab,
                                                 float* __restrict__ e) {
  int t = blockIdx.x * 256 + threadIdx.x;      // E0*32 threads
  int i = t >> 5, q = (t & 31) << 2;
  float4 s = {0.f, 0.f, 0.f, 0.f};
#pragma unroll
  for (int j = 0; j < 3; ++j) {
    int r = bi[i * 3 + j];
    float4 a = *(const float4*)&tab[r * D + q];
    s.x += a.x; s.y += a.y; s.z += a.z; s.w += a.w;
  }
  *(float4*)&e[i * D + q] = s;
}

// ---------- GEMM: C[M][128] = A[M][128] @ W[128][128] (+bias) ----------
__global__ __launch_bounds__(256) void k_gemm128(const float* __restrict__ A,
                                                 const float* __restrict__ W,
                                                 const float* __restrict__ bias,
                                                 float* __restrict__ C) {
  __shared__ float As[64][36];
  __shared__ float Ws[32][132];
  const int t  = threadIdx.x;
  const int m0 = blockIdx.x * 64;
  const int rg = t >> 4, cg = t & 15;
  const int c0 = cg * 4, c1 = 64 + cg * 4;
  float acc[4][8] = {};
  for (int k0 = 0; k0 < 128; k0 += 32) {
    for (int q = t; q < 512; q += 256) {           // A tile 64x32
      int r = q >> 3, cc = (q & 7) << 2;
      *(float4*)&As[r][cc] = *(const float4*)&A[(m0 + r) * 128 + k0 + cc];
    }
    for (int q = t; q < 1024; q += 256) {          // W tile 32x128
      int r = q >> 5, cc = (q & 31) << 2;
      *(float4*)&Ws[r][cc] = *(const float4*)&W[(k0 + r) * 128 + cc];
    }
    __syncthreads();
#pragma unroll 8
    for (int k = 0; k < 32; ++k) {
      float a[4] = {As[rg * 4 + 0][k], As[rg * 4 + 1][k],
                    As[rg * 4 + 2][k], As[rg * 4 + 3][k]};
      float4 w0 = *(float4*)&Ws[k][c0];
      float4 w1 = *(float4*)&Ws[k][c1];
#pragma unroll
      for (int i2 = 0; i2 < 4; ++i2) {
        acc[i2][0] += a[i2] * w0.x; acc[i2][1] += a[i2] * w0.y;
        acc[i2][2] += a[i2] * w0.z; acc[i2][3] += a[i2] * w0.w;
        acc[i2][4] += a[i2] * w1.x; acc[i2][5] += a[i2] * w1.y;
        acc[i2][6] += a[i2] * w1.z; acc[i2][7] += a[i2] * w1.w;
      }
    }
    __syncthreads();
  }
  float4 b0 = {0.f,0.f,0.f,0.f}, b1 = {0.f,0.f,0.f,0.f};
  if (bias) { b0 = *(const float4*)&bias[c0]; b1 = *(const float4*)&bias[c1]; }
#pragma unroll
  for (int i2 = 0; i2 < 4; ++i2) {
    int r = m0 + rg * 4 + i2;
    float4 o0 = {acc[i2][0]+b0.x, acc[i2][1]+b0.y, acc[i2][2]+b0.z, acc[i2][3]+b0.w};
    float4 o1 = {acc[i2][4]+b1.x, acc[i2][5]+b1.y, acc[i2][6]+b1.z, acc[i2][7]+b1.w};
    *(float4*)&C[r * 128 + c0] = o0;
    *(float4*)&C[r * 128 + c1] = o1;
  }
}

// ---------- fused GCN layer, col-half split, 2 blocks/graph, 512 thr.
//            Branch-free chunked edge loop (8 waves). ----------
template <int EG, bool HAS_EW>
__global__ __launch_bounds__(512, 4) void k_gcn_fused(const int* __restrict__ ei, int E,
                                                      const float* __restrict__ e,
                                                      const float* __restrict__ h,
                                                      const float* __restrict__ ew,
                                                      const float* __restrict__ root,
                                                      float* __restrict__ x,
                                                      float* __restrict__ xs) {
  constexpr int NW = 8;
  constexpr int NE_FULL = EG / NW;            // slots where ALL waves valid
  constexpr int TAIL = EG - NE_FULL * NW;     // extra edges for waves w < TAIL
  constexpr int CH = 8;
  constexpr int NCH = NE_FULL / CH;
  constexpr int REM = NE_FULL % CH;
  __shared__ float acc[256 * 64];             // 64 KB
  __shared__ float degs[256];
  __shared__ int   pke[EG];
  __shared__ float redm[512], reds[512];
  const int bid = blockIdx.x;
  const int g = bid >> 1, half = bid & 1;
  const int t = threadIdx.x, w = t >> 6, lane = t & 63;
  const int col = half * 64 + lane;
  const float* egp = e + (size_t)g * EG * 128 + col;
  const float* hgp = h + (size_t)g * 256 * 128 + col;

  float4* a4 = (float4*)acc;
  float4 zero4 = {0.f, 0.f, 0.f, 0.f};
  for (int i = t; i < 4096; i += 512) a4[i] = zero4;
  if (t < 256) degs[t] = 0.f;
  __syncthreads();

  // stage packed indices + degree count (src only)
  for (int j = t; j < EG; j += 512) {
    int s = ei[g * EG + j] & 255, d = ei[E + g * EG + j] & 255;
    pke[j] = s | (d << 8);
    atomicAdd(&degs[s], 1.f);
  }
  __syncthreads();

  // full chunks: unconditional batched loads
  for (int c = 0; c < NCH; ++c) {
    int pp[CH]; float ea[CH], ha[CH], wv[CH];
#pragma unroll
    for (int u = 0; u < CH; ++u) {
      int j = w + (c * CH + u) * NW;
      pp[u] = pke[j];
      ea[u] = egp[(size_t)j * 128];
      ha[u] = hgp[(size_t)(pp[u] & 255) * 128];
      if (HAS_EW) wv[u] = ew[g * EG + j];
    }
#pragma unroll
    for (int u = 0; u < CH; ++u) {
      int s = pp[u] & 255, d = (pp[u] >> 8) & 255;
      float coef = rsqrtf((degs[s] + 1.f) * (degs[d] + 1.f));
      if (HAS_EW) coef *= wv[u];
      atomicAdd(&acc[d * 64 + lane], coef * fmaxf(ha[u] + ea[u], 0.f));
    }
  }
  if constexpr (REM > 0) {
    int pp[REM ? REM : 1]; float ea[REM ? REM : 1], ha[REM ? REM : 1], wv[REM ? REM : 1];
#pragma unroll
    for (int u = 0; u < REM; ++u) {
      int j = w + (NCH * CH + u) * NW;
      pp[u] = pke[j];
      ea[u] = egp[(size_t)j * 128];
      ha[u] = hgp[(size_t)(pp[u] & 255) * 128];
      if (HAS_EW) wv[u] = ew[g * EG + j];
    }
#pragma unroll
    for (int u = 0; u < REM; ++u) {
      int s = pp[u] & 255, d = (pp[u] >> 8) & 255;
      float coef = rsqrtf((degs[s] + 1.f) * (degs[d] + 1.f));
      if (HAS_EW) coef *= wv[u];
      atomicAdd(&acc[d * 64 + lane], coef * fmaxf(ha[u] + ea[u], 0.f));
    }
  }
  if constexpr (TAIL > 0) {
    if (w < TAIL) {                 // wave-uniform branch
      int j = w + NE_FULL * NW;
      int p = pke[j];
      float eav = egp[(size_t)j * 128];
      float hav = hgp[(size_t)(p & 255) * 128];
      float wvv = HAS_EW ? ew[g * EG + j] : 1.f;
      int s = p & 255, d = (p >> 8) & 255;
      float coef = rsqrtf((degs[s] + 1.f) * (degs[d] + 1.f));
      if (HAS_EW) coef *= wvv;
      atomicAdd(&acc[d * 64 + lane], coef * fmaxf(hav + eav, 0.f));
    }
  }
  __syncthreads();

  // finalize: x = relu(acc + relu(h+root)/deg); keep in LDS for readout
  for (int i = t; i < 4096; i += 512) {
    int n = i >> 4, c4 = (i & 15) << 2;
    float inv = 1.f / (degs[n] + 1.f);
    size_t gi = (size_t)(g * 256 + n) * 128 + half * 64 + c4;
    float4 hv = *(const float4*)&h[gi];
    float4 rv = *(const float4*)&root[half * 64 + c4];
    float4 av = a4[i];
    float4 xv;
    xv.x = fmaxf(av.x + fmaxf(hv.x + rv.x, 0.f) * inv, 0.f);
    xv.y = fmaxf(av.y + fmaxf(hv.y + rv.y, 0.f) * inv, 0.f);
    xv.z = fmaxf(av.z + fmaxf(hv.z + rv.z, 0.f) * inv, 0.f);
    xv.w = fmaxf(av.w + fmaxf(hv.w + rv.w, 0.f) * inv, 0.f);
    *(float4*)&x[gi] = xv;
    a4[i] = xv;
  }
  __syncthreads();

  // readout: 8 partials per column
  {
    int c = t & 63, r = t >> 6;
    float mx = -1e30f, sm = 0.f;
    for (int n = r; n < 256; n += 8) {
      float v = acc[n * 64 + c];
      mx = fmaxf(mx, v); sm += v;
    }
    redm[t] = mx; reds[t] = sm;
  }
  __syncthreads();
  if (t < 64) {
    float M = redm[t], S2 = reds[t];
#pragma unroll
    for (int k = 1; k < 8; ++k) {
      M = fmaxf(M, redm[k * 64 + t]);
      S2 += reds[k * 64 + t];
    }
    int cc = half * 64 + t;
    xs[g * 384 + cc]       += M;
    xs[g * 384 + 128 + cc] += S2 * (1.f / 256.f);
    xs[g * 384 + 256 + cc] += S2;
  }
}

// ---------- fused hyperconv: scatter + gather + eout. Col-half split,
//            2 blocks/graph, 512 thr, branch-free chunked loops. ----------
template <int EG>
__global__ __launch_bounds__(512, 4) void k_hyper_fused(const int* __restrict__ ei, int E,
                                                        const float* __restrict__ z,
                                                        const float* __restrict__ bias,
                                                        float* __restrict__ eout) {
  constexpr int NW = 8;
  constexpr int NE_FULL = EG / NW;
  constexpr int TAIL = EG - NE_FULL * NW;
  constexpr int CH = 16;
  constexpr int NCH = NE_FULL / CH;
  constexpr int REM = NE_FULL % CH;
  __shared__ float S[256 * 64];               // 64 KB
  __shared__ float bcs[256];
  __shared__ int   pke[EG];
  const int bid = blockIdx.x;
  const int g = bid >> 1, half = bid & 1;
  const int t = threadIdx.x, w = t >> 6, lane = t & 63;
  const int col = half * 64 + lane;
  const float* zgp = z + (size_t)g * EG * 128 + col;
  float* eop = eout + (size_t)g * EG * 128 + col;

  float4* s4 = (float4*)S;
  float4 zero4 = {0.f, 0.f, 0.f, 0.f};
  for (int i = t; i < 4096; i += 512) s4[i] = zero4;
  if (t < 256) bcs[t] = 0.f;
  __syncthreads();

  for (int j = t; j < EG; j += 512) {
    int s = ei[g * EG + j] & 255, d = ei[E + g * EG + j] & 255;
    pke[j] = s | (d << 8);
    atomicAdd(&bcs[s], 1.f);
    atomicAdd(&bcs[d], 1.f);
  }
  __syncthreads();

  // ---- scatter S += z (both endpoints) ----
  for (int c = 0; c < NCH; ++c) {
    int pp[CH]; float zv[CH];
#pragma unroll
    for (int u = 0; u < CH; ++u) {
      int j = w + (c * CH + u) * NW;
      pp[u] = pke[j];
      zv[u] = zgp[(size_t)j * 128];
    }
#pragma unroll
    for (int u = 0; u < CH; ++u) {
      atomicAdd(&S[(pp[u] & 255) * 64 + lane], zv[u]);
      atomicAdd(&S[((pp[u] >> 8) & 255) * 64 + lane], zv[u]);
    }
  }
  if constexpr (REM > 0) {
    int pp[REM ? REM : 1]; float zv[REM ? REM : 1];
#pragma unroll
    for (int u = 0; u < REM; ++u) {
      int j = w + (NCH * CH + u) * NW;
      pp[u] = pke[j];
      zv[u] = zgp[(size_t)j * 128];
    }
#pragma unroll
    for (int u = 0; u < REM; ++u) {
      atomicAdd(&S[(pp[u] & 255) * 64 + lane], zv[u]);
      atomicAdd(&S[((pp[u] >> 8) & 255) * 64 + lane], zv[u]);
    }
  }
  if constexpr (TAIL > 0) {
    if (w < TAIL) {
      int j = w + NE_FULL * NW;
      int p = pke[j];
      float zv0 = zgp[(size_t)j * 128];
      atomicAdd(&S[(p & 255) * 64 + lane], zv0);
      atomicAdd(&S[((p >> 8) & 255) * 64 + lane], zv0);
    }
  }
  __syncthreads();

  // ---- gather + eout ----
  const float bb = bias[col];
  for (int c = 0; c < NCH; ++c) {
    int pp[CH]; float zv[CH];
#pragma unroll
    for (int u = 0; u < CH; ++u) {
      int j = w + (c * CH + u) * NW;
      pp[u] = pke[j];
      zv[u] = zgp[(size_t)j * 128];
    }
#pragma unroll
    for (int u = 0; u < CH; ++u) {
      int j = w + (c * CH + u) * NW;
      int s = pp[u] & 255, d = (pp[u] >> 8) & 255;
      float bs = bcs[s], bd = bcs[d];
      float bis  = (bs != 1.f) ? 1.f / bs : 0.f;
      float bid_ = (bd != 1.f) ? 1.f / bd : 0.f;
      float dinv = 1.f / (1.f + (bs != 1.f ? 1.f : 0.f) + (bd != 1.f ? 1.f : 0.f));
      float o = fmaxf(dinv * (S[s * 64 + lane] * bis + S[d * 64 + lane] * bid_ + zv[u]) + bb, 0.f);
      eop[(size_t)j * 128] = o;
    }
  }
  if constexpr (REM > 0) {
    int pp[REM ? REM : 1]; float zv[REM ? REM : 1];
#pragma unroll
    for (int u = 0; u < REM; ++u) {
      int j = w + (NCH * CH + u) * NW;
      pp[u] = pke[j];
      zv[u] = zgp[(size_t)j * 128];
    }
#pragma unroll
    for (int u = 0; u < REM; ++u) {
      int j = w + (NCH * CH + u) * NW;
      int s = pp[u] & 255, d = (pp[u] >> 8) & 255;
      float bs = bcs[s], bd = bcs[d];
      float bis  = (bs != 1.f) ? 1.f / bs : 0.f;
      float bid_ = (bd != 1.f) ? 1.f / bd : 0.f;
      float dinv = 1.f / (1.f + (bs != 1.f ? 1.f : 0.f) + (bd != 1.f ? 1.f : 0.f));
      float o = fmaxf(dinv * (S[s * 64 + lane] * bis + S[d * 64 + lane] * bid_ + zv[u]) + bb, 0.f);
      eop[(size_t)j * 128] = o;
    }
  }
  if constexpr (TAIL > 0) {
    if (w < TAIL) {
      int j = w + NE_FULL * NW;
      int p = pke[j];
      float zv0 = zgp[(size_t)j * 128];
      int s = p & 255, d = (p >> 8) & 255;
      float bs = bcs[s], bd = bcs[d];
      float bis  = (bs != 1.f) ? 1.f / bs : 0.f;
      float bid_ = (bd != 1.f) ? 1.f / bd : 0.f;
      float dinv = 1.f / (1.f + (bs != 1.f ? 1.f : 0.f) + (bd != 1.f ? 1.f : 0.f));
      float o = fmaxf(dinv * (S[s * 64 + lane] * bis + S[d * 64 + lane] * bid_ + zv0) + bb, 0.f);
      eop[(size_t)j * 128] = o;
    }
  }
}

// ---------- score dot: zs[i] = e[i] . wsc  (4 lanes per row) ----------
__global__ __launch_bounds__(256) void k_sdot(const float* __restrict__ e,
                                              const float* __restrict__ wsc,
                                              float* __restrict__ zs, int E) {
  int t = threadIdx.x, wv = t >> 6, lane = t & 63;
  int row = blockIdx.x * 64 + wv * 16 + (lane >> 2);
  int sub = lane & 3;
  if (row >= E) return;
  const float4* ep = (const float4*)(e + (size_t)row * 128) + sub;
  const float4* wp = (const float4*)wsc + sub;
  float s = 0.f;
#pragma unroll
  for (int k = 0; k < 8; ++k) {
    float4 a = ep[k * 4], b = wp[k * 4];
    s += a.x * b.x + a.y * b.y + a.z * b.z + a.w * b.w;
  }
  s += __shfl_xor(s, 1);
  s += __shfl_xor(s, 2);
  if (sub == 0) zs[row] = s;
}

// ---------- per-graph score finalize + top-k sort + compaction ----------
template <int EG, int KEEP, int ENEW>
__global__ __launch_bounds__(256) void k_sortcompact(const float* __restrict__ zs,
                                                     const int* __restrict__ ei_old, int E_old,
                                                     const float* __restrict__ bsc,
                                                     const float* __restrict__ e_old,
                                                     int* __restrict__ ei_new,
                                                     float* __restrict__ e_new,
                                                     float* __restrict__ ew) {
  __shared__ float ss[512];
  __shared__ int   si[512];
  __shared__ int   pke[512];
  __shared__ float Ssh[256], bcs[256];
  int g = blockIdx.x, t = threadIdx.x;
  if (t < 256) { Ssh[t] = 0.f; bcs[t] = 0.f; }
  __syncthreads();
  for (int j = t; j < EG; j += 256) {
    int s = ei_old[g * EG + j] & 255, d = ei_old[E_old + g * EG + j] & 255;
    pke[j] = s | (d << 8);
    atomicAdd(&bcs[s], 1.f);
    atomicAdd(&bcs[d], 1.f);
  }
  __syncthreads();
  for (int j = t; j < EG; j += 256) {
    float v = zs[g * EG + j];
    atomicAdd(&Ssh[pke[j] & 255], v);
    atomicAdd(&Ssh[(pke[j] >> 8) & 255], v);
  }
  __syncthreads();
  float bsc0 = bsc[0];
  for (int i = t; i < 512; i += 256) {
    if (i < EG) {
      int s = pke[i] & 255, d = (pke[i] >> 8) & 255;
      float bs = bcs[s], bd = bcs[d];
      float bis  = (bs != 1.f) ? 1.f / bs : 0.f;
      float bid_ = (bd != 1.f) ? 1.f / bd : 0.f;
      float dn = 1.f + (bs != 1.f ? 1.f : 0.f) + (bd != 1.f ? 1.f : 0.f);
      ss[i] = tanhf((Ssh[s] * bis + Ssh[d] * bid_ + zs[g * EG + i]) / dn + bsc0);
      si[i] = i;
    } else { ss[i] = -INFINITY; si[i] = 0x7FFFFFFF; }
  }
  __syncthreads();
  for (int k = 2; k <= 512; k <<= 1) {
    for (int j = k >> 1; j > 0; j >>= 1) {
      for (int i = t; i < 512; i += 256) {
        int ixj = i ^ j;
        if (ixj > i) {
          float s1 = ss[i], s2 = ss[ixj];
          int i1 = si[i], i2 = si[ixj];
          bool firstBetter = (s1 > s2) || (s1 == s2 && i1 < i2);
          bool desc = ((i & k) == 0);
          if (desc != firstBetter) {
            ss[i] = s2; si[i] = i2; ss[ixj] = s1; si[ixj] = i1;
          }
        }
      }
      __syncthreads();
    }
  }
  for (int j = t; j < KEEP; j += 256) {
    int oldp = g * EG + si[j];
    int newp = g * KEEP + j;
    ei_new[newp]        = ei_old[oldp];
    ei_new[ENEW + newp] = ei_old[E_old + oldp];
    ew[newp] = fminf(fmaxf(ss[j], 0.f), 1.f);
  }
  __syncthreads();
  for (int q = t; q < KEEP * 32; q += 256) {
    int j = q >> 5, c4 = (q & 31) << 2;
    *(float4*)&e_new[(size_t)(g * KEEP + j) * 128 + c4] =
        *(const float4*)&e_old[(size_t)(g * EG + si[j]) * 128 + c4];
  }
}

// ---------- final MLP ----------
__global__ __launch_bounds__(128) void k_mlp(const float* __restrict__ xs,
                                             const float* __restrict__ Wc1, const float* __restrict__ bc1,
                                             const float* __restrict__ Wc2, const float* __restrict__ bc2,
                                             const float* __restrict__ Wc3, const float* __restrict__ bc3,
                                             float* __restrict__ out) {
  __shared__ float row[384];
  __shared__ float h1[128];
  __shared__ float h2[64];
  int g = blockIdx.x, t = threadIdx.x;
  for (int i = t; i < 384; i += 128) row[i] = xs[g * 384 + i];
  __syncthreads();
  float a = bc1[t];
  for (int k = 0; k < 384; ++k) a += row[k] * Wc1[k * 128 + t];
  h1[t] = fmaxf(a, 0.f);
  __syncthreads();
  if (t < 64) {
    float b = bc2[t];
    for (int k = 0; k < 128; ++k) b += h1[k] * Wc2[k * 64 + t];
    h2[t] = fmaxf(b, 0.f);
  }
  __syncthreads();
  float o = bc3[t];
  for (int k = 0; k < 64; ++k) o += h2[k] * Wc3[k * 128 + t];
  out[g * 128 + t] = o;
}

extern "C" void kernel_launch(void* const* d_in, const int* in_sizes, int n_in,
                              void* d_out, int out_size, void* d_ws, size_t ws_size,
                              hipStream_t stream) {
  (void)in_sizes; (void)n_in; (void)out_size; (void)ws_size;
  const int*   x_idx  = (const int*)d_in[0];
  const int*   b_idx  = (const int*)d_in[1];
  const int*   ei0    = (const int*)d_in[2];
  const float* atom_t = (const float*)d_in[4];
  const float* bond_t = (const float*)d_in[5];
  const float* W_gcn  = (const float*)d_in[6];
  const float* b_gcn  = (const float*)d_in[7];
  const float* root   = (const float*)d_in[8];
  const float* W_hyp  = (const float*)d_in[9];
  const float* b_hyp  = (const float*)d_in[10];
  const float* W_sc   = (const float*)d_in[11];
  const float* b_sc   = (const float*)d_in[12];
  const float* Wc1    = (const float*)d_in[13];
  const float* bc1_   = (const float*)d_in[14];
  const float* Wc2    = (const float*)d_in[15];
  const float* bc2_   = (const float*)d_in[16];
  const float* Wc3    = (const float*)d_in[17];
  const float* bc3_   = (const float*)d_in[18];
  float* out = (float*)d_out;

  // workspace layout
  float* x    = (float*)d_ws;
  float* h    = x    + (size_t)NTOT * D;
  float* eA   = h    + (size_t)NTOT * D;
  float* eB   = eA   + (size_t)E0 * D;
  float* zs   = eB   + (size_t)E0 * D;
  float* ew   = zs   + E0;
  float* xs   = ew   + E0;
  int*   eiB  = (int*)(xs + BG * 384);
  int*   eiA2 = eiB + 2 * E0;

  hipMemsetAsync(xs, 0, BG * 384 * 4, stream);
  k_embed_x<<<NTOT * 32 / 256, 256, 0, stream>>>(x_idx, atom_t, x);
  k_embed_e<<<E0 * 32 / 256, 256, 0, stream>>>(b_idx, bond_t, eA);

  // ---- layer 0 ----
  k_gemm128<<<NTOT / 64, 256, 0, stream>>>(x, W_gcn, b_gcn, h);
  k_gcn_fused<EG0, false><<<2 * BG, 512, 0, stream>>>(ei0, E0, eA, h, nullptr, root, x, xs);
  k_gemm128<<<E0 / 64, 256, 0, stream>>>(eA, W_hyp, nullptr, eB);
  k_hyper_fused<EG0><<<2 * BG, 512, 0, stream>>>(ei0, E0, eB, b_hyp, eA);
  k_sdot<<<E0 / 64, 256, 0, stream>>>(eA, W_sc, zs, E0);
  k_sortcompact<EG0, KP0, E1><<<BG, 256, 0, stream>>>(zs, ei0, E0, b_sc, eA, eiB, eB, ew);

  // ---- layer 1 ----
  k_gemm128<<<NTOT / 64, 256, 0, stream>>>(x, W_gcn + D * D, b_gcn + D, h);
  k_gcn_fused<KP0, true><<<2 * BG, 512, 0, stream>>>(eiB, E1, eB, h, ew, root + D, x, xs);
  k_gemm128<<<E1 / 64, 256, 0, stream>>>(eB, W_hyp + D * D, nullptr, eA);
  k_hyper_fused<KP0><<<2 * BG, 512, 0, stream>>>(eiB, E1, eA, b_hyp + D, eB);
  k_sdot<<<E1 / 64, 256, 0, stream>>>(eB, W_sc + D, zs, E1);
  k_sortcompact<KP0, KP1, E2><<<BG, 256, 0, stream>>>(zs, eiB, E1, b_sc + 1, eB, eiA2, eA, ew);

  // ---- layer 2 ----
  k_gemm128<<<NTOT / 64, 256, 0, stream>>>(x, W_gcn + 2 * D * D, b_gcn + 2 * D, h);
  k_gcn_fused<KP1, true><<<2 * BG, 512, 0, stream>>>(eiA2, E2, eA, h, ew, root + 2 * D, x, xs);

  k_mlp<<<BG, 128, 0, stream>>>(xs, Wc1, bc1_, Wc2, bc2_, Wc3, bc3_, out);
}

// Round 8
// 575.314 us; speedup vs baseline: 1.7841x; 1.6218x over previous
//
#include <hip/hip_runtime.h>
#include <math.h>

constexpr int NTOT = 65536;
constexpr int D    = 128;
constexpr int BG   = 256;
constexpr int E0 = 131072, E1 = 104960, E2 = 83968;
constexpr int EG0 = 512;
constexpr int KP0 = 410, KP1 = 328;

// ---------- embeddings ----------
__global__ __launch_bounds__(256) void k_embed_x(const int* __restrict__ xi,
                                                 const float* __restrict__ tab,
                                                 float* __restrict__ x) {
  int t = blockIdx.x * 256 + threadIdx.x;      // NTOT*32 threads
  int v = t >> 5, q = (t & 31) << 2;
  float4 s = {0.f, 0.f, 0.f, 0.f};
#pragma unroll
  for (int j = 0; j < 9; ++j) {
    int r = xi[v * 9 + j];
    float4 a = *(const float4*)&tab[r * D + q];
    s.x += a.x; s.y += a.y; s.z += a.z; s.w += a.w;
  }
  *(float4*)&x[v * D + q] = s;
}

__global__ __launch_bounds__(256) void k_embed_e(const int* __restrict__ bi,
                                                 const float* __restrict__ tab,
                                                 float* __restrict__ e) {
  int t = blockIdx.x * 256 + threadIdx.x;      // E0*32 threads
  int i = t >> 5, q = (t & 31) << 2;
  float4 s = {0.f, 0.f, 0.f, 0.f};
#pragma unroll
  for (int j = 0; j < 3; ++j) {
    int r = bi[i * 3 + j];
    float4 a = *(const float4*)&tab[r * D + q];
    s.x += a.x; s.y += a.y; s.z += a.z; s.w += a.w;
  }
  *(float4*)&e[i * D + q] = s;
}

// ---------- GEMM: C[M][128] = A[M][128] @ W[128][128] (+bias) ----------
__global__ __launch_bounds__(256) void k_gemm128(const float* __restrict__ A,
                                                 const float* __restrict__ W,
                                                 const float* __restrict__ bias,
                                                 float* __restrict__ C) {
  __shared__ float As[64][36];
  __shared__ float Ws[32][132];
  const int t  = threadIdx.x;
  const int m0 = blockIdx.x * 64;
  const int rg = t >> 4, cg = t & 15;
  const int c0 = cg * 4, c1 = 64 + cg * 4;
  float acc[4][8] = {};
  for (int k0 = 0; k0 < 128; k0 += 32) {
    for (int q = t; q < 512; q += 256) {           // A tile 64x32
      int r = q >> 3, cc = (q & 7) << 2;
      *(float4*)&As[r][cc] = *(const float4*)&A[(m0 + r) * 128 + k0 + cc];
    }
    for (int q = t; q < 1024; q += 256) {          // W tile 32x128
      int r = q >> 5, cc = (q & 31) << 2;
      *(float4*)&Ws[r][cc] = *(const float4*)&W[(k0 + r) * 128 + cc];
    }
    __syncthreads();
#pragma unroll 8
    for (int k = 0; k < 32; ++k) {
      float a[4] = {As[rg * 4 + 0][k], As[rg * 4 + 1][k],
                    As[rg * 4 + 2][k], As[rg * 4 + 3][k]};
      float4 w0 = *(float4*)&Ws[k][c0];
      float4 w1 = *(float4*)&Ws[k][c1];
#pragma unroll
      for (int i2 = 0; i2 < 4; ++i2) {
        acc[i2][0] += a[i2] * w0.x; acc[i2][1] += a[i2] * w0.y;
        acc[i2][2] += a[i2] * w0.z; acc[i2][3] += a[i2] * w0.w;
        acc[i2][4] += a[i2] * w1.x; acc[i2][5] += a[i2] * w1.y;
        acc[i2][6] += a[i2] * w1.z; acc[i2][7] += a[i2] * w1.w;
      }
    }
    __syncthreads();
  }
  float4 b0 = {0.f,0.f,0.f,0.f}, b1 = {0.f,0.f,0.f,0.f};
  if (bias) { b0 = *(const float4*)&bias[c0]; b1 = *(const float4*)&bias[c1]; }
#pragma unroll
  for (int i2 = 0; i2 < 4; ++i2) {
    int r = m0 + rg * 4 + i2;
    float4 o0 = {acc[i2][0]+b0.x, acc[i2][1]+b0.y, acc[i2][2]+b0.z, acc[i2][3]+b0.w};
    float4 o1 = {acc[i2][4]+b1.x, acc[i2][5]+b1.y, acc[i2][6]+b1.z, acc[i2][7]+b1.w};
    *(float4*)&C[r * 128 + c0] = o0;
    *(float4*)&C[r * 128 + c1] = o1;
  }
}

// ---------- fused GCN layer, col-half split, 2 blocks/graph, 512 thr.
//            CSR-grouped accumulation — NO wave-wide LDS float atomics. ----------
template <int EG, bool HAS_EW>
__global__ __launch_bounds__(512, 4) void k_gcn_fused(const int* __restrict__ ei, int E,
                                                      const float* __restrict__ e,
                                                      const float* __restrict__ h,
                                                      const float* __restrict__ ew,
                                                      const float* __restrict__ root,
                                                      float* __restrict__ x,
                                                      float* __restrict__ xs) {
  constexpr int NW = 8;
  __shared__ float acc[256 * 64];             // 64 KB
  __shared__ int   pke[EG];
  __shared__ int   cnts[256];                 // src counts (deg-1)
  __shared__ int   cntd[256];                 // dst counts (CSR)
  __shared__ int   off[257];
  __shared__ int   cur[256];
  __shared__ short adj[EG];
  __shared__ float redm[512], reds[512];
  const int bid = blockIdx.x;
  const int g = bid >> 1, half = bid & 1;
  const int t = threadIdx.x, w = t >> 6, lane = t & 63;
  const int col = half * 64 + lane;
  const float* egp = e + (size_t)g * EG * 128 + col;
  const float* hgp = h + (size_t)g * 256 * 128 + col;

  if (t < 256) { cnts[t] = 0; cntd[t] = 0; }
  __syncthreads();

  for (int j = t; j < EG; j += 512) {
    int s = ei[g * EG + j] & 255, d = ei[E + g * EG + j] & 255;
    pke[j] = s | (d << 8);
    atomicAdd(&cnts[s], 1);
    atomicAdd(&cntd[d], 1);
  }
  __syncthreads();

  // exclusive scan: off[n] = sum_{m<n} cntd[m]
  if (t < 256) off[t + 1] = cntd[t];
  if (t == 0) off[0] = 0;
  __syncthreads();
  for (int st = 1; st < 256; st <<= 1) {
    int add = 0;
    if (t < 256 && t + 1 > st) add = off[t + 1 - st];
    __syncthreads();
    if (t < 256) off[t + 1] += add;
    __syncthreads();
  }
  if (t < 256) cur[t] = off[t];
  __syncthreads();

  for (int j = t; j < EG; j += 512) {
    int d = (pke[j] >> 8) & 255;
    int pos = atomicAdd(&cur[d], 1);
    adj[pos] = (short)j;
  }
  __syncthreads();

  // accumulate per dst node: plain register reduction, one ds_write per node
  for (int n = w; n < 256; n += NW) {
    float dd = (float)cnts[n] + 1.f;
    float val = 0.f;
    int b0 = off[n], b1 = off[n + 1];
    int k = b0;
    for (; k + 1 < b1; k += 2) {
      int j0 = adj[k], j1 = adj[k + 1];
      int p0 = pke[j0], p1 = pke[j1];
      int s0 = p0 & 255, s1 = p1 & 255;
      float e0 = egp[(size_t)j0 * 128], e1v = egp[(size_t)j1 * 128];
      float h0 = hgp[(size_t)s0 * 128], h1 = hgp[(size_t)s1 * 128];
      float c0 = rsqrtf(((float)cnts[s0] + 1.f) * dd);
      float c1 = rsqrtf(((float)cnts[s1] + 1.f) * dd);
      if (HAS_EW) { c0 *= ew[g * EG + j0]; c1 *= ew[g * EG + j1]; }
      val += c0 * fmaxf(h0 + e0, 0.f) + c1 * fmaxf(h1 + e1v, 0.f);
    }
    if (k < b1) {
      int j0 = adj[k];
      int p0 = pke[j0];
      int s0 = p0 & 255;
      float c0 = rsqrtf(((float)cnts[s0] + 1.f) * dd);
      if (HAS_EW) c0 *= ew[g * EG + j0];
      val += c0 * fmaxf(hgp[(size_t)s0 * 128] + egp[(size_t)j0 * 128], 0.f);
    }
    acc[n * 64 + lane] = val;
  }
  __syncthreads();

  // finalize: x = relu(acc + relu(h+root)/deg); keep in LDS for readout
  float4* a4 = (float4*)acc;
  for (int i = t; i < 4096; i += 512) {
    int n = i >> 4, c4 = (i & 15) << 2;
    float inv = 1.f / ((float)cnts[n] + 1.f);
    size_t gi = (size_t)(g * 256 + n) * 128 + half * 64 + c4;
    float4 hv = *(const float4*)&h[gi];
    float4 rv = *(const float4*)&root[half * 64 + c4];
    float4 av = a4[i];
    float4 xv;
    xv.x = fmaxf(av.x + fmaxf(hv.x + rv.x, 0.f) * inv, 0.f);
    xv.y = fmaxf(av.y + fmaxf(hv.y + rv.y, 0.f) * inv, 0.f);
    xv.z = fmaxf(av.z + fmaxf(hv.z + rv.z, 0.f) * inv, 0.f);
    xv.w = fmaxf(av.w + fmaxf(hv.w + rv.w, 0.f) * inv, 0.f);
    *(float4*)&x[gi] = xv;
    a4[i] = xv;
  }
  __syncthreads();

  // readout: 8 partials per column
  {
    int c = t & 63, r = t >> 6;
    float mx = -1e30f, sm = 0.f;
    for (int n = r; n < 256; n += 8) {
      float v = acc[n * 64 + c];
      mx = fmaxf(mx, v); sm += v;
    }
    redm[t] = mx; reds[t] = sm;
  }
  __syncthreads();
  if (t < 64) {
    float M = redm[t], S2 = reds[t];
#pragma unroll
    for (int k = 1; k < 8; ++k) {
      M = fmaxf(M, redm[k * 64 + t]);
      S2 += reds[k * 64 + t];
    }
    int cc = half * 64 + t;
    xs[g * 384 + cc]       += M;
    xs[g * 384 + 128 + cc] += S2 * (1.f / 256.f);
    xs[g * 384 + 256 + cc] += S2;
  }
}

// ---------- fused hyperconv: CSR-grouped incidence accumulation (no float
//            atomics) + gather + eout. Col-half split, 2 blocks/graph. ----------
template <int EG>
__global__ __launch_bounds__(512, 4) void k_hyper_fused(const int* __restrict__ ei, int E,
                                                        const float* __restrict__ z,
                                                        const float* __restrict__ bias,
                                                        float* __restrict__ eout) {
  constexpr int NW = 8;
  __shared__ float S[256 * 64];               // 64 KB
  __shared__ int   pke[EG];
  __shared__ int   cnt[256];                  // incidence counts == bc
  __shared__ int   off[257];
  __shared__ int   cur[256];
  __shared__ short adj[2 * EG];
  const int bid = blockIdx.x;
  const int g = bid >> 1, half = bid & 1;
  const int t = threadIdx.x, w = t >> 6, lane = t & 63;
  const int col = half * 64 + lane;
  const float* zgp = z + (size_t)g * EG * 128 + col;
  float* eop = eout + (size_t)g * EG * 128 + col;

  if (t < 256) cnt[t] = 0;
  __syncthreads();

  for (int j = t; j < EG; j += 512) {
    int s = ei[g * EG + j] & 255, d = ei[E + g * EG + j] & 255;
    pke[j] = s | (d << 8);
    atomicAdd(&cnt[s], 1);
    atomicAdd(&cnt[d], 1);
  }
  __syncthreads();

  if (t < 256) off[t + 1] = cnt[t];
  if (t == 0) off[0] = 0;
  __syncthreads();
  for (int st = 1; st < 256; st <<= 1) {
    int add = 0;
    if (t < 256 && t + 1 > st) add = off[t + 1 - st];
    __syncthreads();
    if (t < 256) off[t + 1] += add;
    __syncthreads();
  }
  if (t < 256) cur[t] = off[t];
  __syncthreads();

  for (int j = t; j < EG; j += 512) {
    int p = pke[j];
    int pos0 = atomicAdd(&cur[p & 255], 1);
    adj[pos0] = (short)j;
    int pos1 = atomicAdd(&cur[(p >> 8) & 255], 1);
    adj[pos1] = (short)j;
  }
  __syncthreads();

  // accumulate per node: S[n] = sum of z over incident edges (plain adds)
  for (int n = w; n < 256; n += NW) {
    float val = 0.f;
    int b0 = off[n], b1 = off[n + 1];
    int k = b0;
    for (; k + 1 < b1; k += 2) {
      float a = zgp[(size_t)adj[k] * 128];
      float b = zgp[(size_t)adj[k + 1] * 128];
      val += a + b;
    }
    if (k < b1) val += zgp[(size_t)adj[k] * 128];
    S[n * 64 + lane] = val;
  }
  __syncthreads();

  // gather + eout (plain LDS reads)
  const float bb = bias[col];
  for (int j = w; j < EG; j += NW) {
    int p = pke[j];
    int s = p & 255, d = (p >> 8) & 255;
    float bs = (float)cnt[s], bd = (float)cnt[d];
    float bis  = (bs != 1.f) ? 1.f / bs : 0.f;
    float bid_ = (bd != 1.f) ? 1.f / bd : 0.f;
    float dinv = 1.f / (1.f + (bs != 1.f ? 1.f : 0.f) + (bd != 1.f ? 1.f : 0.f));
    float o = fmaxf(dinv * (S[s * 64 + lane] * bis + S[d * 64 + lane] * bid_ + zgp[(size_t)j * 128]) + bb, 0.f);
    eop[(size_t)j * 128] = o;
  }
}

// ---------- score dot: zs[i] = e[i] . wsc  (4 lanes per row) ----------
__global__ __launch_bounds__(256) void k_sdot(const float* __restrict__ e,
                                              const float* __restrict__ wsc,
                                              float* __restrict__ zs, int E) {
  int t = threadIdx.x, wv = t >> 6, lane = t & 63;
  int row = blockIdx.x * 64 + wv * 16 + (lane >> 2);
  int sub = lane & 3;
  if (row >= E) return;
  const float4* ep = (const float4*)(e + (size_t)row * 128) + sub;
  const float4* wp = (const float4*)wsc + sub;
  float s = 0.f;
#pragma unroll
  for (int k = 0; k < 8; ++k) {
    float4 a = ep[k * 4], b = wp[k * 4];
    s += a.x * b.x + a.y * b.y + a.z * b.z + a.w * b.w;
  }
  s += __shfl_xor(s, 1);
  s += __shfl_xor(s, 2);
  if (sub == 0) zs[row] = s;
}

// ---------- per-graph score finalize + top-k sort + compaction ----------
template <int EG, int KEEP, int ENEW>
__global__ __launch_bounds__(256) void k_sortcompact(const float* __restrict__ zs,
                                                     const int* __restrict__ ei_old, int E_old,
                                                     const float* __restrict__ bsc,
                                                     const float* __restrict__ e_old,
                                                     int* __restrict__ ei_new,
                                                     float* __restrict__ e_new,
                                                     float* __restrict__ ew) {
  __shared__ float ss[512];
  __shared__ int   si[512];
  __shared__ int   pke[512];
  __shared__ float Ssh[256], bcs[256];
  int g = blockIdx.x, t = threadIdx.x;
  if (t < 256) { Ssh[t] = 0.f; bcs[t] = 0.f; }
  __syncthreads();
  for (int j = t; j < EG; j += 256) {
    int s = ei_old[g * EG + j] & 255, d = ei_old[E_old + g * EG + j] & 255;
    pke[j] = s | (d << 8);
    atomicAdd(&bcs[s], 1.f);
    atomicAdd(&bcs[d], 1.f);
  }
  __syncthreads();
  for (int j = t; j < EG; j += 256) {
    float v = zs[g * EG + j];
    atomicAdd(&Ssh[pke[j] & 255], v);
    atomicAdd(&Ssh[(pke[j] >> 8) & 255], v);
  }
  __syncthreads();
  float bsc0 = bsc[0];
  for (int i = t; i < 512; i += 256) {
    if (i < EG) {
      int s = pke[i] & 255, d = (pke[i] >> 8) & 255;
      float bs = bcs[s], bd = bcs[d];
      float bis  = (bs != 1.f) ? 1.f / bs : 0.f;
      float bid_ = (bd != 1.f) ? 1.f / bd : 0.f;
      float dn = 1.f + (bs != 1.f ? 1.f : 0.f) + (bd != 1.f ? 1.f : 0.f);
      ss[i] = tanhf((Ssh[s] * bis + Ssh[d] * bid_ + zs[g * EG + i]) / dn + bsc0);
      si[i] = i;
    } else { ss[i] = -INFINITY; si[i] = 0x7FFFFFFF; }
  }
  __syncthreads();
  for (int k = 2; k <= 512; k <<= 1) {
    for (int j = k >> 1; j > 0; j >>= 1) {
      for (int i = t; i < 512; i += 256) {
        int ixj = i ^ j;
        if (ixj > i) {
          float s1 = ss[i], s2 = ss[ixj];
          int i1 = si[i], i2 = si[ixj];
          bool firstBetter = (s1 > s2) || (s1 == s2 && i1 < i2);
          bool desc = ((i & k) == 0);
          if (desc != firstBetter) {
            ss[i] = s2; si[i] = i2; ss[ixj] = s1; si[ixj] = i1;
          }
        }
      }
      __syncthreads();
    }
  }
  for (int j = t; j < KEEP; j += 256) {
    int oldp = g * EG + si[j];
    int newp = g * KEEP + j;
    ei_new[newp]        = ei_old[oldp];
    ei_new[ENEW + newp] = ei_old[E_old + oldp];
    ew[newp] = fminf(fmaxf(ss[j], 0.f), 1.f);
  }
  __syncthreads();
  for (int q = t; q < KEEP * 32; q += 256) {
    int j = q >> 5, c4 = (q & 31) << 2;
    *(float4*)&e_new[(size_t)(g * KEEP + j) * 128 + c4] =
        *(const float4*)&e_old[(size_t)(g * EG + si[j]) * 128 + c4];
  }
}

// ---------- final MLP ----------
__global__ __launch_bounds__(128) void k_mlp(const float* __restrict__ xs,
                                             const float* __restrict__ Wc1, const float* __restrict__ bc1,
                                             const float* __restrict__ Wc2, const float* __restrict__ bc2,
                                             const float* __restrict__ Wc3, const float* __restrict__ bc3,
                                             float* __restrict__ out) {
  __shared__ float row[384];
  __shared__ float h1[128];
  __shared__ float h2[64];
  int g = blockIdx.x, t = threadIdx.x;
  for (int i = t; i < 384; i += 128) row[i] = xs[g * 384 + i];
  __syncthreads();
  float a = bc1[t];
  for (int k = 0; k < 384; ++k) a += row[k] * Wc1[k * 128 + t];
  h1[t] = fmaxf(a, 0.f);
  __syncthreads();
  if (t < 64) {
    float b = bc2[t];
    for (int k = 0; k < 128; ++k) b += h1[k] * Wc2[k * 64 + t];
    h2[t] = fmaxf(b, 0.f);
  }
  __syncthreads();
  float o = bc3[t];
  for (int k = 0; k < 64; ++k) o += h2[k] * Wc3[k * 128 + t];
  out[g * 128 + t] = o;
}

extern "C" void kernel_launch(void* const* d_in, const int* in_sizes, int n_in,
                              void* d_out, int out_size, void* d_ws, size_t ws_size,
                              hipStream_t stream) {
  (void)in_sizes; (void)n_in; (void)out_size; (void)ws_size;
  const int*   x_idx  = (const int*)d_in[0];
  const int*   b_idx  = (const int*)d_in[1];
  const int*   ei0    = (const int*)d_in[2];
  const float* atom_t = (const float*)d_in[4];
  const float* bond_t = (const float*)d_in[5];
  const float* W_gcn  = (const float*)d_in[6];
  const float* b_gcn  = (const float*)d_in[7];
  const float* root   = (const float*)d_in[8];
  const float* W_hyp  = (const float*)d_in[9];
  const float* b_hyp  = (const float*)d_in[10];
  const float* W_sc   = (const float*)d_in[11];
  const float* b_sc   = (const float*)d_in[12];
  const float* Wc1    = (const float*)d_in[13];
  const float* bc1_   = (const float*)d_in[14];
  const float* Wc2    = (const float*)d_in[15];
  const float* bc2_   = (const float*)d_in[16];
  const float* Wc3    = (const float*)d_in[17];
  const float* bc3_   = (const float*)d_in[18];
  float* out = (float*)d_out;

  // workspace layout
  float* x    = (float*)d_ws;
  float* h    = x    + (size_t)NTOT * D;
  float* eA   = h    + (size_t)NTOT * D;
  float* eB   = eA   + (size_t)E0 * D;
  float* zs   = eB   + (size_t)E0 * D;
  float* ew   = zs   + E0;
  float* xs   = ew   + E0;
  int*   eiB  = (int*)(xs + BG * 384);
  int*   eiA2 = eiB + 2 * E0;

  hipMemsetAsync(xs, 0, BG * 384 * 4, stream);
  k_embed_x<<<NTOT * 32 / 256, 256, 0, stream>>>(x_idx, atom_t, x);
  k_embed_e<<<E0 * 32 / 256, 256, 0, stream>>>(b_idx, bond_t, eA);

  // ---- layer 0 ----
  k_gemm128<<<NTOT / 64, 256, 0, stream>>>(x, W_gcn, b_gcn, h);
  k_gcn_fused<EG0, false><<<2 * BG, 512, 0, stream>>>(ei0, E0, eA, h, nullptr, root, x, xs);
  k_gemm128<<<E0 / 64, 256, 0, stream>>>(eA, W_hyp, nullptr, eB);
  k_hyper_fused<EG0><<<2 * BG, 512, 0, stream>>>(ei0, E0, eB, b_hyp, eA);
  k_sdot<<<E0 / 64, 256, 0, stream>>>(eA, W_sc, zs, E0);
  k_sortcompact<EG0, KP0, E1><<<BG, 256, 0, stream>>>(zs, ei0, E0, b_sc, eA, eiB, eB, ew);

  // ---- layer 1 ----
  k_gemm128<<<NTOT / 64, 256, 0, stream>>>(x, W_gcn + D * D, b_gcn + D, h);
  k_gcn_fused<KP0, true><<<2 * BG, 512, 0, stream>>>(eiB, E1, eB, h, ew, root + D, x, xs);
  k_gemm128<<<E1 / 64, 256, 0, stream>>>(eB, W_hyp + D * D, nullptr, eA);
  k_hyper_fused<KP0><<<2 * BG, 512, 0, stream>>>(eiB, E1, eA, b_hyp + D, eB);
  k_sdot<<<E1 / 64, 256, 0, stream>>>(eB, W_sc + D, zs, E1);
  k_sortcompact<KP0, KP1, E2><<<BG, 256, 0, stream>>>(zs, eiB, E1, b_sc + 1, eB, eiA2, eA, ew);

  // ---- layer 2 ----
  k_gemm128<<<NTOT / 64, 256, 0, stream>>>(x, W_gcn + 2 * D * D, b_gcn + 2 * D, h);
  k_gcn_fused<KP1, true><<<2 * BG, 512, 0, stream>>>(eiA2, E2, eA, h, ew, root + 2 * D, x, xs);

  k_mlp<<<BG, 128, 0, stream>>>(xs, Wc1, bc1_, Wc2, bc2_, Wc3, bc3_, out);
}

// Round 9
// 475.264 us; speedup vs baseline: 2.1597x; 1.2105x over previous
//
#include <hip/hip_runtime.h>
#include <hip/hip_bf16.h>
#include <math.h>

constexpr int NTOT = 65536;
constexpr int D    = 128;
constexpr int BG   = 256;
constexpr int E0 = 131072, E1 = 104960, E2 = 83968;
constexpr int EG0 = 512;
constexpr int KP0 = 410, KP1 = 328;

typedef __bf16 bf16x8 __attribute__((ext_vector_type(8)));
typedef float  f32x4  __attribute__((ext_vector_type(4)));

// ---------- embeddings ----------
__global__ __launch_bounds__(256) void k_embed_x(const int* __restrict__ xi,
                                                 const float* __restrict__ tab,
                                                 float* __restrict__ x) {
  int t = blockIdx.x * 256 + threadIdx.x;      // NTOT*32 threads
  int v = t >> 5, q = (t & 31) << 2;
  float4 s = {0.f, 0.f, 0.f, 0.f};
#pragma unroll
  for (int j = 0; j < 9; ++j) {
    int r = xi[v * 9 + j];
    float4 a = *(const float4*)&tab[r * D + q];
    s.x += a.x; s.y += a.y; s.z += a.z; s.w += a.w;
  }
  *(float4*)&x[v * D + q] = s;
}

__global__ __launch_bounds__(256) void k_embed_e(const int* __restrict__ bi,
                                                 const float* __restrict__ tab,
                                                 float* __restrict__ e) {
  int t = blockIdx.x * 256 + threadIdx.x;      // E0*32 threads
  int i = t >> 5, q = (t & 31) << 2;
  float4 s = {0.f, 0.f, 0.f, 0.f};
#pragma unroll
  for (int j = 0; j < 3; ++j) {
    int r = bi[i * 3 + j];
    float4 a = *(const float4*)&tab[r * D + q];
    s.x += a.x; s.y += a.y; s.z += a.z; s.w += a.w;
  }
  *(float4*)&e[i * D + q] = s;
}

// ---------- bf16 MFMA GEMM: C[M][128] = A[M][128] @ W[128][128] (+bias)
//            128-row tile per block, 4 waves x 32 rows. M % 128 == 0. ----------
__global__ __launch_bounds__(256) void k_gemm_bf16(const float* __restrict__ A,
                                                   const float* __restrict__ W,
                                                   const float* __restrict__ bias,
                                                   float* __restrict__ C) {
  __shared__ bf16x8 Wl[4][8][64];              // [ks][nt][lane] fragments, 32 KB
  const int t = threadIdx.x, w = t >> 6, lane = t & 63;
  const int m0 = blockIdx.x * 128;

  // stage W: f32 global -> bf16 fragment-order LDS.
  // frag (ks,nt,l): elem b is W[ks*32 + (l>>4)*8 + b][nt*16 + (l&15)]
  // (A staging uses the SAME (group,elem)->k map, so any HW k-permutation cancels.)
  bf16x8* Wf = (bf16x8*)Wl;
  for (int q = t; q < 2048; q += 256) {
    int ks = q >> 9, nt = (q >> 6) & 7, l = q & 63;
    int kk = ks * 32 + ((l >> 4) << 3);
    int nn = nt * 16 + (l & 15);
    const float* wp = W + (size_t)kk * 128 + nn;
    bf16x8 v;
#pragma unroll
    for (int b = 0; b < 8; ++b) v[b] = (__bf16)wp[(size_t)b * 128];
    Wf[q] = v;
  }

  // A fragments: rows w*32+(lane&15) and +16; k-chunk (lane>>4)*8 + ks*32
  const int r0 = m0 + w * 32 + (lane & 15);
  const float* Ap0 = A + (size_t)r0 * 128 + ((lane >> 4) << 3);
  const float* Ap1 = Ap0 + 16 * 128;
  bf16x8 a0[4], a1[4];
#pragma unroll
  for (int ks = 0; ks < 4; ++ks) {
    float4 x0 = *(const float4*)(Ap0 + ks * 32);
    float4 x1 = *(const float4*)(Ap0 + ks * 32 + 4);
    float4 y0 = *(const float4*)(Ap1 + ks * 32);
    float4 y1 = *(const float4*)(Ap1 + ks * 32 + 4);
    bf16x8 u, v;
    u[0] = (__bf16)x0.x; u[1] = (__bf16)x0.y; u[2] = (__bf16)x0.z; u[3] = (__bf16)x0.w;
    u[4] = (__bf16)x1.x; u[5] = (__bf16)x1.y; u[6] = (__bf16)x1.z; u[7] = (__bf16)x1.w;
    v[0] = (__bf16)y0.x; v[1] = (__bf16)y0.y; v[2] = (__bf16)y0.z; v[3] = (__bf16)y0.w;
    v[4] = (__bf16)y1.x; v[5] = (__bf16)y1.y; v[6] = (__bf16)y1.z; v[7] = (__bf16)y1.w;
    a0[ks] = u; a1[ks] = v;
  }
  __syncthreads();

  f32x4 acc0[8] = {}; f32x4 acc1[8] = {};
#pragma unroll
  for (int ks = 0; ks < 4; ++ks) {
#pragma unroll
    for (int nt = 0; nt < 8; ++nt) {
      bf16x8 b = Wl[ks][nt][lane];
      acc0[nt] = __builtin_amdgcn_mfma_f32_16x16x32_bf16(a0[ks], b, acc0[nt], 0, 0, 0);
      acc1[nt] = __builtin_amdgcn_mfma_f32_16x16x32_bf16(a1[ks], b, acc1[nt], 0, 0, 0);
    }
  }

  // epilogue: C/D layout col=lane&15, row=(lane>>4)*4+reg  [HW-verified]
  const int orow = m0 + w * 32 + ((lane >> 4) << 2);
  const int ocol = lane & 15;
#pragma unroll
  for (int nt = 0; nt < 8; ++nt) {
    float bb = bias ? bias[nt * 16 + ocol] : 0.f;
    float* cp = C + (size_t)orow * 128 + nt * 16 + ocol;
#pragma unroll
    for (int r = 0; r < 4; ++r) {
      cp[(size_t)r * 128]        = acc0[nt][r] + bb;
      cp[(size_t)(16 + r) * 128] = acc1[nt][r] + bb;
    }
  }
}

// ---------- fused GCN layer, col-half split, 2 blocks/graph, 512 thr.
//            CSR-grouped accumulation — NO wave-wide LDS float atomics. ----------
template <int EG, bool HAS_EW>
__global__ __launch_bounds__(512, 4) void k_gcn_fused(const int* __restrict__ ei, int E,
                                                      const float* __restrict__ e,
                                                      const float* __restrict__ h,
                                                      const float* __restrict__ ew,
                                                      const float* __restrict__ root,
                                                      float* __restrict__ x,
                                                      float* __restrict__ xs) {
  constexpr int NW = 8;
  __shared__ float acc[256 * 64];             // 64 KB
  __shared__ int   pke[EG];
  __shared__ int   cnts[256];                 // src counts (deg-1)
  __shared__ int   cntd[256];                 // dst counts (CSR)
  __shared__ int   off[257];
  __shared__ int   cur[256];
  __shared__ short adj[EG];
  __shared__ float redm[512], reds[512];
  const int bid = blockIdx.x;
  const int g = bid >> 1, half = bid & 1;
  const int t = threadIdx.x, w = t >> 6, lane = t & 63;
  const int col = half * 64 + lane;
  const float* egp = e + (size_t)g * EG * 128 + col;
  const float* hgp = h + (size_t)g * 256 * 128 + col;

  if (t < 256) { cnts[t] = 0; cntd[t] = 0; }
  __syncthreads();

  for (int j = t; j < EG; j += 512) {
    int s = ei[g * EG + j] & 255, d = ei[E + g * EG + j] & 255;
    pke[j] = s | (d << 8);
    atomicAdd(&cnts[s], 1);
    atomicAdd(&cntd[d], 1);
  }
  __syncthreads();

  // exclusive scan: off[n] = sum_{m<n} cntd[m]
  if (t < 256) off[t + 1] = cntd[t];
  if (t == 0) off[0] = 0;
  __syncthreads();
  for (int st = 1; st < 256; st <<= 1) {
    int add = 0;
    if (t < 256 && t + 1 > st) add = off[t + 1 - st];
    __syncthreads();
    if (t < 256) off[t + 1] += add;
    __syncthreads();
  }
  if (t < 256) cur[t] = off[t];
  __syncthreads();

  for (int j = t; j < EG; j += 512) {
    int d = (pke[j] >> 8) & 255;
    int pos = atomicAdd(&cur[d], 1);
    adj[pos] = (short)j;
  }
  __syncthreads();

  // accumulate per dst node: plain register reduction, one ds_write per node
  for (int n = w; n < 256; n += NW) {
    float dd = (float)cnts[n] + 1.f;
    float val = 0.f;
    int b0 = off[n], b1 = off[n + 1];
    int k = b0;
    for (; k + 1 < b1; k += 2) {
      int j0 = adj[k], j1 = adj[k + 1];
      int p0 = pke[j0], p1 = pke[j1];
      int s0 = p0 & 255, s1 = p1 & 255;
      float e0 = egp[(size_t)j0 * 128], e1v = egp[(size_t)j1 * 128];
      float h0 = hgp[(size_t)s0 * 128], h1 = hgp[(size_t)s1 * 128];
      float c0 = rsqrtf(((float)cnts[s0] + 1.f) * dd);
      float c1 = rsqrtf(((float)cnts[s1] + 1.f) * dd);
      if (HAS_EW) { c0 *= ew[g * EG + j0]; c1 *= ew[g * EG + j1]; }
      val += c0 * fmaxf(h0 + e0, 0.f) + c1 * fmaxf(h1 + e1v, 0.f);
    }
    if (k < b1) {
      int j0 = adj[k];
      int p0 = pke[j0];
      int s0 = p0 & 255;
      float c0 = rsqrtf(((float)cnts[s0] + 1.f) * dd);
      if (HAS_EW) c0 *= ew[g * EG + j0];
      val += c0 * fmaxf(hgp[(size_t)s0 * 128] + egp[(size_t)j0 * 128], 0.f);
    }
    acc[n * 64 + lane] = val;
  }
  __syncthreads();

  // finalize: x = relu(acc + relu(h+root)/deg); keep in LDS for readout
  float4* a4 = (float4*)acc;
  for (int i = t; i < 4096; i += 512) {
    int n = i >> 4, c4 = (i & 15) << 2;
    float inv = 1.f / ((float)cnts[n] + 1.f);
    size_t gi = (size_t)(g * 256 + n) * 128 + half * 64 + c4;
    float4 hv = *(const float4*)&h[gi];
    float4 rv = *(const float4*)&root[half * 64 + c4];
    float4 av = a4[i];
    float4 xv;
    xv.x = fmaxf(av.x + fmaxf(hv.x + rv.x, 0.f) * inv, 0.f);
    xv.y = fmaxf(av.y + fmaxf(hv.y + rv.y, 0.f) * inv, 0.f);
    xv.z = fmaxf(av.z + fmaxf(hv.z + rv.z, 0.f) * inv, 0.f);
    xv.w = fmaxf(av.w + fmaxf(hv.w + rv.w, 0.f) * inv, 0.f);
    *(float4*)&x[gi] = xv;
    a4[i] = xv;
  }
  __syncthreads();

  // readout: 8 partials per column
  {
    int c = t & 63, r = t >> 6;
    float mx = -1e30f, sm = 0.f;
    for (int n = r; n < 256; n += 8) {
      float v = acc[n * 64 + c];
      mx = fmaxf(mx, v); sm += v;
    }
    redm[t] = mx; reds[t] = sm;
  }
  __syncthreads();
  if (t < 64) {
    float M = redm[t], S2 = reds[t];
#pragma unroll
    for (int k = 1; k < 8; ++k) {
      M = fmaxf(M, redm[k * 64 + t]);
      S2 += reds[k * 64 + t];
    }
    int cc = half * 64 + t;
    xs[g * 384 + cc]       += M;
    xs[g * 384 + 128 + cc] += S2 * (1.f / 256.f);
    xs[g * 384 + 256 + cc] += S2;
  }
}

// ---------- fused hyperconv: CSR-grouped incidence accumulation (no float
//            atomics) + gather + eout. Col-half split, 2 blocks/graph. ----------
template <int EG>
__global__ __launch_bounds__(512, 4) void k_hyper_fused(const int* __restrict__ ei, int E,
                                                        const float* __restrict__ z,
                                                        const float* __restrict__ bias,
                                                        float* __restrict__ eout) {
  constexpr int NW = 8;
  __shared__ float S[256 * 64];               // 64 KB
  __shared__ int   pke[EG];
  __shared__ int   cnt[256];                  // incidence counts == bc
  __shared__ int   off[257];
  __shared__ int   cur[256];
  __shared__ short adj[2 * EG];
  const int bid = blockIdx.x;
  const int g = bid >> 1, half = bid & 1;
  const int t = threadIdx.x, w = t >> 6, lane = t & 63;
  const int col = half * 64 + lane;
  const float* zgp = z + (size_t)g * EG * 128 + col;
  float* eop = eout + (size_t)g * EG * 128 + col;

  if (t < 256) cnt[t] = 0;
  __syncthreads();

  for (int j = t; j < EG; j += 512) {
    int s = ei[g * EG + j] & 255, d = ei[E + g * EG + j] & 255;
    pke[j] = s | (d << 8);
    atomicAdd(&cnt[s], 1);
    atomicAdd(&cnt[d], 1);
  }
  __syncthreads();

  if (t < 256) off[t + 1] = cnt[t];
  if (t == 0) off[0] = 0;
  __syncthreads();
  for (int st = 1; st < 256; st <<= 1) {
    int add = 0;
    if (t < 256 && t + 1 > st) add = off[t + 1 - st];
    __syncthreads();
    if (t < 256) off[t + 1] += add;
    __syncthreads();
  }
  if (t < 256) cur[t] = off[t];
  __syncthreads();

  for (int j = t; j < EG; j += 512) {
    int p = pke[j];
    int pos0 = atomicAdd(&cur[p & 255], 1);
    adj[pos0] = (short)j;
    int pos1 = atomicAdd(&cur[(p >> 8) & 255], 1);
    adj[pos1] = (short)j;
  }
  __syncthreads();

  // accumulate per node: S[n] = sum of z over incident edges (plain adds)
  for (int n = w; n < 256; n += NW) {
    float val = 0.f;
    int b0 = off[n], b1 = off[n + 1];
    int k = b0;
    for (; k + 1 < b1; k += 2) {
      float a = zgp[(size_t)adj[k] * 128];
      float b = zgp[(size_t)adj[k + 1] * 128];
      val += a + b;
    }
    if (k < b1) val += zgp[(size_t)adj[k] * 128];
    S[n * 64 + lane] = val;
  }
  __syncthreads();

  // gather + eout (plain LDS reads)
  const float bb = bias[col];
  for (int j = w; j < EG; j += NW) {
    int p = pke[j];
    int s = p & 255, d = (p >> 8) & 255;
    float bs = (float)cnt[s], bd = (float)cnt[d];
    float bis  = (bs != 1.f) ? 1.f / bs : 0.f;
    float bid_ = (bd != 1.f) ? 1.f / bd : 0.f;
    float dinv = 1.f / (1.f + (bs != 1.f ? 1.f : 0.f) + (bd != 1.f ? 1.f : 0.f));
    float o = fmaxf(dinv * (S[s * 64 + lane] * bis + S[d * 64 + lane] * bid_ + zgp[(size_t)j * 128]) + bb, 0.f);
    eop[(size_t)j * 128] = o;
  }
}

// ---------- score dot: zs[i] = e[i] . wsc  (4 lanes per row) ----------
__global__ __launch_bounds__(256) void k_sdot(const float* __restrict__ e,
                                              const float* __restrict__ wsc,
                                              float* __restrict__ zs, int E) {
  int t = threadIdx.x, wv = t >> 6, lane = t & 63;
  int row = blockIdx.x * 64 + wv * 16 + (lane >> 2);
  int sub = lane & 3;
  if (row >= E) return;
  const float4* ep = (const float4*)(e + (size_t)row * 128) + sub;
  const float4* wp = (const float4*)wsc + sub;
  float s = 0.f;
#pragma unroll
  for (int k = 0; k < 8; ++k) {
    float4 a = ep[k * 4], b = wp[k * 4];
    s += a.x * b.x + a.y * b.y + a.z * b.z + a.w * b.w;
  }
  s += __shfl_xor(s, 1);
  s += __shfl_xor(s, 2);
  if (sub == 0) zs[row] = s;
}

// ---------- per-graph score finalize + top-k sort + compaction ----------
template <int EG, int KEEP, int ENEW>
__global__ __launch_bounds__(256) void k_sortcompact(const float* __restrict__ zs,
                                                     const int* __restrict__ ei_old, int E_old,
                                                     const float* __restrict__ bsc,
                                                     const float* __restrict__ e_old,
                                                     int* __restrict__ ei_new,
                                                     float* __restrict__ e_new,
                                                     float* __restrict__ ew) {
  __shared__ float ss[512];
  __shared__ int   si[512];
  __shared__ int   pke[512];
  __shared__ float Ssh[256], bcs[256];
  int g = blockIdx.x, t = threadIdx.x;
  if (t < 256) { Ssh[t] = 0.f; bcs[t] = 0.f; }
  __syncthreads();
  for (int j = t; j < EG; j += 256) {
    int s = ei_old[g * EG + j] & 255, d = ei_old[E_old + g * EG + j] & 255;
    pke[j] = s | (d << 8);
    atomicAdd(&bcs[s], 1.f);
    atomicAdd(&bcs[d], 1.f);
  }
  __syncthreads();
  for (int j = t; j < EG; j += 256) {
    float v = zs[g * EG + j];
    atomicAdd(&Ssh[pke[j] & 255], v);
    atomicAdd(&Ssh[(pke[j] >> 8) & 255], v);
  }
  __syncthreads();
  float bsc0 = bsc[0];
  for (int i = t; i < 512; i += 256) {
    if (i < EG) {
      int s = pke[i] & 255, d = (pke[i] >> 8) & 255;
      float bs = bcs[s], bd = bcs[d];
      float bis  = (bs != 1.f) ? 1.f / bs : 0.f;
      float bid_ = (bd != 1.f) ? 1.f / bd : 0.f;
      float dn = 1.f + (bs != 1.f ? 1.f : 0.f) + (bd != 1.f ? 1.f : 0.f);
      ss[i] = tanhf((Ssh[s] * bis + Ssh[d] * bid_ + zs[g * EG + i]) / dn + bsc0);
      si[i] = i;
    } else { ss[i] = -INFINITY; si[i] = 0x7FFFFFFF; }
  }
  __syncthreads();
  for (int k = 2; k <= 512; k <<= 1) {
    for (int j = k >> 1; j > 0; j >>= 1) {
      for (int i = t; i < 512; i += 256) {
        int ixj = i ^ j;
        if (ixj > i) {
          float s1 = ss[i], s2 = ss[ixj];
          int i1 = si[i], i2 = si[ixj];
          bool firstBetter = (s1 > s2) || (s1 == s2 && i1 < i2);
          bool desc = ((i & k) == 0);
          if (desc != firstBetter) {
            ss[i] = s2; si[i] = i2; ss[ixj] = s1; si[ixj] = i1;
          }
        }
      }
      __syncthreads();
    }
  }
  for (int j = t; j < KEEP; j += 256) {
    int oldp = g * EG + si[j];
    int newp = g * KEEP + j;
    ei_new[newp]        = ei_old[oldp];
    ei_new[ENEW + newp] = ei_old[E_old + oldp];
    ew[newp] = fminf(fmaxf(ss[j], 0.f), 1.f);
  }
  __syncthreads();
  for (int q = t; q < KEEP * 32; q += 256) {
    int j = q >> 5, c4 = (q & 31) << 2;
    *(float4*)&e_new[(size_t)(g * KEEP + j) * 128 + c4] =
        *(const float4*)&e_old[(size_t)(g * EG + si[j]) * 128 + c4];
  }
}

// ---------- final MLP ----------
__global__ __launch_bounds__(128) void k_mlp(const float* __restrict__ xs,
                                             const float* __restrict__ Wc1, const float* __restrict__ bc1,
                                             const float* __restrict__ Wc2, const float* __restrict__ bc2,
                                             const float* __restrict__ Wc3, const float* __restrict__ bc3,
                                             float* __restrict__ out) {
  __shared__ float row[384];
  __shared__ float h1[128];
  __shared__ float h2[64];
  int g = blockIdx.x, t = threadIdx.x;
  for (int i = t; i < 384; i += 128) row[i] = xs[g * 384 + i];
  __syncthreads();
  float a = bc1[t];
  for (int k = 0; k < 384; ++k) a += row[k] * Wc1[k * 128 + t];
  h1[t] = fmaxf(a, 0.f);
  __syncthreads();
  if (t < 64) {
    float b = bc2[t];
    for (int k = 0; k < 128; ++k) b += h1[k] * Wc2[k * 64 + t];
    h2[t] = fmaxf(b, 0.f);
  }
  __syncthreads();
  float o = bc3[t];
  for (int k = 0; k < 64; ++k) o += h2[k] * Wc3[k * 128 + t];
  out[g * 128 + t] = o;
}

extern "C" void kernel_launch(void* const* d_in, const int* in_sizes, int n_in,
                              void* d_out, int out_size, void* d_ws, size_t ws_size,
                              hipStream_t stream) {
  (void)in_sizes; (void)n_in; (void)out_size; (void)ws_size;
  const int*   x_idx  = (const int*)d_in[0];
  const int*   b_idx  = (const int*)d_in[1];
  const int*   ei0    = (const int*)d_in[2];
  const float* atom_t = (const float*)d_in[4];
  const float* bond_t = (const float*)d_in[5];
  const float* W_gcn  = (const float*)d_in[6];
  const float* b_gcn  = (const float*)d_in[7];
  const float* root   = (const float*)d_in[8];
  const float* W_hyp  = (const float*)d_in[9];
  const float* b_hyp  = (const float*)d_in[10];
  const float* W_sc   = (const float*)d_in[11];
  const float* b_sc   = (const float*)d_in[12];
  const float* Wc1    = (const float*)d_in[13];
  const float* bc1_   = (const float*)d_in[14];
  const float* Wc2    = (const float*)d_in[15];
  const float* bc2_   = (const float*)d_in[16];
  const float* Wc3    = (const float*)d_in[17];
  const float* bc3_   = (const float*)d_in[18];
  float* out = (float*)d_out;

  // workspace layout
  float* x    = (float*)d_ws;
  float* h    = x    + (size_t)NTOT * D;
  float* eA   = h    + (size_t)NTOT * D;
  float* eB   = eA   + (size_t)E0 * D;
  float* zs   = eB   + (size_t)E0 * D;
  float* ew   = zs   + E0;
  float* xs   = ew   + E0;
  int*   eiB  = (int*)(xs + BG * 384);
  int*   eiA2 = eiB + 2 * E0;

  hipMemsetAsync(xs, 0, BG * 384 * 4, stream);
  k_embed_x<<<NTOT * 32 / 256, 256, 0, stream>>>(x_idx, atom_t, x);
  k_embed_e<<<E0 * 32 / 256, 256, 0, stream>>>(b_idx, bond_t, eA);

  // ---- layer 0 ----
  k_gemm_bf16<<<NTOT / 128, 256, 0, stream>>>(x, W_gcn, b_gcn, h);
  k_gcn_fused<EG0, false><<<2 * BG, 512, 0, stream>>>(ei0, E0, eA, h, nullptr, root, x, xs);
  k_gemm_bf16<<<E0 / 128, 256, 0, stream>>>(eA, W_hyp, nullptr, eB);
  k_hyper_fused<EG0><<<2 * BG, 512, 0, stream>>>(ei0, E0, eB, b_hyp, eA);
  k_sdot<<<E0 / 64, 256, 0, stream>>>(eA, W_sc, zs, E0);
  k_sortcompact<EG0, KP0, E1><<<BG, 256, 0, stream>>>(zs, ei0, E0, b_sc, eA, eiB, eB, ew);

  // ---- layer 1 ----
  k_gemm_bf16<<<NTOT / 128, 256, 0, stream>>>(x, W_gcn + D * D, b_gcn + D, h);
  k_gcn_fused<KP0, true><<<2 * BG, 512, 0, stream>>>(eiB, E1, eB, h, ew, root + D, x, xs);
  k_gemm_bf16<<<E1 / 128, 256, 0, stream>>>(eB, W_hyp + D * D, nullptr, eA);
  k_hyper_fused<KP0><<<2 * BG, 512, 0, stream>>>(eiB, E1, eA, b_hyp + D, eB);
  k_sdot<<<E1 / 64, 256, 0, stream>>>(eB, W_sc + D, zs, E1);
  k_sortcompact<KP0, KP1, E2><<<BG, 256, 0, stream>>>(zs, eiB, E1, b_sc + 1, eB, eiA2, eA, ew);

  // ---- layer 2 ----
  k_gemm_bf16<<<NTOT / 128, 256, 0, stream>>>(x, W_gcn + 2 * D * D, b_gcn + 2 * D, h);
  k_gcn_fused<KP1, true><<<2 * BG, 512, 0, stream>>>(eiA2, E2, eA, h, ew, root + 2 * D, x, xs);

  k_mlp<<<BG, 128, 0, stream>>>(xs, Wc1, bc1_, Wc2, bc2_, Wc3, bc3_, out);
}

// Round 10
// 409.515 us; speedup vs baseline: 2.5065x; 1.1606x over previous
//
#include <hip/hip_runtime.h>
#include <hip/hip_bf16.h>
#include <math.h>

constexpr int NTOT = 65536;
constexpr int D    = 128;
constexpr int BG   = 256;
constexpr int E0 = 131072, E1 = 104960, E2 = 83968;
constexpr int EG0 = 512;
constexpr int KP0 = 410, KP1 = 328;

typedef __bf16 bf16x8 __attribute__((ext_vector_type(8)));
typedef float  f32x4  __attribute__((ext_vector_type(4)));

// ---------- embeddings ----------
__global__ __launch_bounds__(256) void k_embed_x(const int* __restrict__ xi,
                                                 const float* __restrict__ tab,
                                                 float* __restrict__ x) {
  int t = blockIdx.x * 256 + threadIdx.x;      // NTOT*32 threads
  int v = t >> 5, q = (t & 31) << 2;
  float4 s = {0.f, 0.f, 0.f, 0.f};
#pragma unroll
  for (int j = 0; j < 9; ++j) {
    int r = xi[v * 9 + j];
    float4 a = *(const float4*)&tab[r * D + q];
    s.x += a.x; s.y += a.y; s.z += a.z; s.w += a.w;
  }
  *(float4*)&x[v * D + q] = s;
}

__global__ __launch_bounds__(256) void k_embed_e(const int* __restrict__ bi,
                                                 const float* __restrict__ tab,
                                                 float* __restrict__ e) {
  int t = blockIdx.x * 256 + threadIdx.x;      // E0*32 threads
  int i = t >> 5, q = (t & 31) << 2;
  float4 s = {0.f, 0.f, 0.f, 0.f};
#pragma unroll
  for (int j = 0; j < 3; ++j) {
    int r = bi[i * 3 + j];
    float4 a = *(const float4*)&tab[r * D + q];
    s.x += a.x; s.y += a.y; s.z += a.z; s.w += a.w;
  }
  *(float4*)&e[i * D + q] = s;
}

// ---------- bf16 MFMA GEMM: C[M][128] = A[M][128] @ W[128][128] (+bias) ----------
__global__ __launch_bounds__(256) void k_gemm_bf16(const float* __restrict__ A,
                                                   const float* __restrict__ W,
                                                   const float* __restrict__ bias,
                                                   float* __restrict__ C) {
  __shared__ bf16x8 Wl[4][8][64];              // [ks][nt][lane] fragments, 32 KB
  const int t = threadIdx.x, w = t >> 6, lane = t & 63;
  const int m0 = blockIdx.x * 128;

  bf16x8* Wf = (bf16x8*)Wl;
  for (int q = t; q < 2048; q += 256) {
    int ks = q >> 9, nt = (q >> 6) & 7, l = q & 63;
    int kk = ks * 32 + ((l >> 4) << 3);
    int nn = nt * 16 + (l & 15);
    const float* wp = W + (size_t)kk * 128 + nn;
    bf16x8 v;
#pragma unroll
    for (int b = 0; b < 8; ++b) v[b] = (__bf16)wp[(size_t)b * 128];
    Wf[q] = v;
  }

  const int r0 = m0 + w * 32 + (lane & 15);
  const float* Ap0 = A + (size_t)r0 * 128 + ((lane >> 4) << 3);
  const float* Ap1 = Ap0 + 16 * 128;
  bf16x8 a0[4], a1[4];
#pragma unroll
  for (int ks = 0; ks < 4; ++ks) {
    float4 x0 = *(const float4*)(Ap0 + ks * 32);
    float4 x1 = *(const float4*)(Ap0 + ks * 32 + 4);
    float4 y0 = *(const float4*)(Ap1 + ks * 32);
    float4 y1 = *(const float4*)(Ap1 + ks * 32 + 4);
    bf16x8 u, v;
    u[0] = (__bf16)x0.x; u[1] = (__bf16)x0.y; u[2] = (__bf16)x0.z; u[3] = (__bf16)x0.w;
    u[4] = (__bf16)x1.x; u[5] = (__bf16)x1.y; u[6] = (__bf16)x1.z; u[7] = (__bf16)x1.w;
    v[0] = (__bf16)y0.x; v[1] = (__bf16)y0.y; v[2] = (__bf16)y0.z; v[3] = (__bf16)y0.w;
    v[4] = (__bf16)y1.x; v[5] = (__bf16)y1.y; v[6] = (__bf16)y1.z; v[7] = (__bf16)y1.w;
    a0[ks] = u; a1[ks] = v;
  }
  __syncthreads();

  f32x4 acc0[8] = {}; f32x4 acc1[8] = {};
#pragma unroll
  for (int ks = 0; ks < 4; ++ks) {
#pragma unroll
    for (int nt = 0; nt < 8; ++nt) {
      bf16x8 b = Wl[ks][nt][lane];
      acc0[nt] = __builtin_amdgcn_mfma_f32_16x16x32_bf16(a0[ks], b, acc0[nt], 0, 0, 0);
      acc1[nt] = __builtin_amdgcn_mfma_f32_16x16x32_bf16(a1[ks], b, acc1[nt], 0, 0, 0);
    }
  }

  const int orow = m0 + w * 32 + ((lane >> 4) << 2);
  const int ocol = lane & 15;
#pragma unroll
  for (int nt = 0; nt < 8; ++nt) {
    float bb = bias ? bias[nt * 16 + ocol] : 0.f;
    float* cp = C + (size_t)orow * 128 + nt * 16 + ocol;
#pragma unroll
    for (int r = 0; r < 4; ++r) {
      cp[(size_t)r * 128]        = acc0[nt][r] + bb;
      cp[(size_t)(16 + r) * 128] = acc1[nt][r] + bb;
    }
  }
}

// ---------- fused GCN layer: 1 block/graph, 1024 thr, full 128 cols (float2/lane).
//            CSR-grouped, per-edge coef precomputed in LDS. ----------
template <int EG, bool HAS_EW>
__global__ __launch_bounds__(1024, 4) void k_gcn_fused(const int* __restrict__ ei, int E,
                                                       const float* __restrict__ e,
                                                       const float* __restrict__ h,
                                                       const float* __restrict__ ew,
                                                       const float* __restrict__ root,
                                                       float* __restrict__ x,
                                                       float* __restrict__ xs) {
  constexpr int NW = 16;
  __shared__ float acc[256 * 128];            // 128 KB
  __shared__ int   pke[EG];
  __shared__ float coef[EG];
  __shared__ int   cnts[256];
  __shared__ int   cntd[256];
  __shared__ int   off[257];
  __shared__ int   cur[256];
  __shared__ short adj[EG];
  __shared__ float redm[1024], reds[1024];
  const int g = blockIdx.x;
  const int t = threadIdx.x, w = t >> 6, lane = t & 63;
  const float2* eg2 = (const float2*)e + (size_t)g * EG * 64 + lane;
  const float2* hg2 = (const float2*)h + (size_t)g * 256 * 64 + lane;
  float2* acc2 = (float2*)acc;

  if (t < 256) { cnts[t] = 0; cntd[t] = 0; }
  __syncthreads();

  for (int j = t; j < EG; j += 1024) {
    int s = ei[g * EG + j] & 255, d = ei[E + g * EG + j] & 255;
    pke[j] = s | (d << 8);
    atomicAdd(&cnts[s], 1);
    atomicAdd(&cntd[d], 1);
  }
  __syncthreads();

  // per-edge coefficient (both endpoints folded in)
  for (int j = t; j < EG; j += 1024) {
    int p = pke[j];
    int s = p & 255, d = (p >> 8) & 255;
    float c = rsqrtf(((float)cnts[s] + 1.f) * ((float)cnts[d] + 1.f));
    if (HAS_EW) c *= ew[g * EG + j];
    coef[j] = c;
  }

  // exclusive scan of cntd
  if (t < 256) off[t + 1] = cntd[t];
  if (t == 0) off[0] = 0;
  __syncthreads();
  for (int st = 1; st < 256; st <<= 1) {
    int add = 0;
    if (t < 256 && t + 1 > st) add = off[t + 1 - st];
    __syncthreads();
    if (t < 256) off[t + 1] += add;
    __syncthreads();
  }
  if (t < 256) cur[t] = off[t];
  __syncthreads();

  for (int j = t; j < EG; j += 1024) {
    int d = (pke[j] >> 8) & 255;
    int pos = atomicAdd(&cur[d], 1);
    adj[pos] = (short)j;
  }
  __syncthreads();

  // accumulate per dst node (float2, plain writes)
  for (int n = w; n < 256; n += NW) {
    float2 val = {0.f, 0.f};
    int b0 = off[n], b1 = off[n + 1];
    int k = b0;
    for (; k + 1 < b1; k += 2) {
      int j0 = adj[k], j1 = adj[k + 1];
      int s0 = pke[j0] & 255, s1 = pke[j1] & 255;
      float2 e0 = eg2[(size_t)j0 * 64], e1 = eg2[(size_t)j1 * 64];
      float2 h0 = hg2[(size_t)s0 * 64], h1 = hg2[(size_t)s1 * 64];
      float c0 = coef[j0], c1 = coef[j1];
      val.x += c0 * fmaxf(h0.x + e0.x, 0.f) + c1 * fmaxf(h1.x + e1.x, 0.f);
      val.y += c0 * fmaxf(h0.y + e0.y, 0.f) + c1 * fmaxf(h1.y + e1.y, 0.f);
    }
    if (k < b1) {
      int j0 = adj[k];
      int s0 = pke[j0] & 255;
      float2 e0 = eg2[(size_t)j0 * 64];
      float2 h0 = hg2[(size_t)s0 * 64];
      float c0 = coef[j0];
      val.x += c0 * fmaxf(h0.x + e0.x, 0.f);
      val.y += c0 * fmaxf(h0.y + e0.y, 0.f);
    }
    acc2[n * 64 + lane] = val;
  }
  __syncthreads();

  // finalize: x = relu(acc + relu(h+root)/deg); keep in LDS for readout
  float4* a4 = (float4*)acc;
  for (int i = t; i < 8192; i += 1024) {
    int n = i >> 5, q = (i & 31) << 2;
    float inv = 1.f / ((float)cnts[n] + 1.f);
    size_t gi = (size_t)(g * 256 + n) * 128 + q;
    float4 hv = *(const float4*)&h[gi];
    float4 rv = *(const float4*)&root[q];
    float4 av = a4[i];
    float4 xv;
    xv.x = fmaxf(av.x + fmaxf(hv.x + rv.x, 0.f) * inv, 0.f);
    xv.y = fmaxf(av.y + fmaxf(hv.y + rv.y, 0.f) * inv, 0.f);
    xv.z = fmaxf(av.z + fmaxf(hv.z + rv.z, 0.f) * inv, 0.f);
    xv.w = fmaxf(av.w + fmaxf(hv.w + rv.w, 0.f) * inv, 0.f);
    *(float4*)&x[gi] = xv;
    a4[i] = xv;
  }
  __syncthreads();

  // readout: 8 partials per column (t = r*128 + c)
  {
    int c = t & 127, r = t >> 7;
    float mx = -1e30f, sm = 0.f;
    for (int n = r; n < 256; n += 8) {
      float v = acc[n * 128 + c];
      mx = fmaxf(mx, v); sm += v;
    }
    redm[t] = mx; reds[t] = sm;
  }
  __syncthreads();
  if (t < 128) {
    float M = redm[t], S2 = reds[t];
#pragma unroll
    for (int k = 1; k < 8; ++k) {
      M = fmaxf(M, redm[k * 128 + t]);
      S2 += reds[k * 128 + t];
    }
    xs[g * 384 + t]       += M;
    xs[g * 384 + 128 + t] += S2 * (1.f / 256.f);
    xs[g * 384 + 256 + t] += S2;
  }
}

// ---------- fused hyperconv: 1 block/graph, 1024 thr, full cols (float2/lane).
//            CSR incidence accumulation + per-edge consts precomputed. ----------
template <int EG>
__global__ __launch_bounds__(1024, 4) void k_hyper_fused(const int* __restrict__ ei, int E,
                                                         const float* __restrict__ z,
                                                         const float* __restrict__ bias,
                                                         float* __restrict__ eout) {
  constexpr int NW = 16;
  __shared__ float S[256 * 128];              // 128 KB
  __shared__ int   pke[EG];
  __shared__ float as_[EG], ad_[EG], az_[EG];
  __shared__ int   cnt[256];
  __shared__ int   off[257];
  __shared__ int   cur[256];
  __shared__ short adj[2 * EG];
  const int g = blockIdx.x;
  const int t = threadIdx.x, w = t >> 6, lane = t & 63;
  const float2* zg2 = (const float2*)z + (size_t)g * EG * 64 + lane;
  float2* eo2 = (float2*)eout + (size_t)g * EG * 64 + lane;
  float2* S2 = (float2*)S;

  if (t < 256) cnt[t] = 0;
  __syncthreads();

  for (int j = t; j < EG; j += 1024) {
    int s = ei[g * EG + j] & 255, d = ei[E + g * EG + j] & 255;
    pke[j] = s | (d << 8);
    atomicAdd(&cnt[s], 1);
    atomicAdd(&cnt[d], 1);
  }
  __syncthreads();

  // per-edge gather constants
  for (int j = t; j < EG; j += 1024) {
    int p = pke[j];
    int s = p & 255, d = (p >> 8) & 255;
    int cs = cnt[s], cd = cnt[d];
    float bis  = (cs != 1) ? 1.f / (float)cs : 0.f;
    float bid_ = (cd != 1) ? 1.f / (float)cd : 0.f;
    float dinv = 1.f / (1.f + (cs != 1 ? 1.f : 0.f) + (cd != 1 ? 1.f : 0.f));
    as_[j] = dinv * bis;
    ad_[j] = dinv * bid_;
    az_[j] = dinv;
  }

  if (t < 256) off[t + 1] = cnt[t];
  if (t == 0) off[0] = 0;
  __syncthreads();
  for (int st = 1; st < 256; st <<= 1) {
    int add = 0;
    if (t < 256 && t + 1 > st) add = off[t + 1 - st];
    __syncthreads();
    if (t < 256) off[t + 1] += add;
    __syncthreads();
  }
  if (t < 256) cur[t] = off[t];
  __syncthreads();

  for (int j = t; j < EG; j += 1024) {
    int p = pke[j];
    int pos0 = atomicAdd(&cur[p & 255], 1);
    adj[pos0] = (short)j;
    int pos1 = atomicAdd(&cur[(p >> 8) & 255], 1);
    adj[pos1] = (short)j;
  }
  __syncthreads();

  // accumulate per node (float2, plain writes)
  for (int n = w; n < 256; n += NW) {
    float2 val = {0.f, 0.f};
    int b0 = off[n], b1 = off[n + 1];
    int k = b0;
    for (; k + 1 < b1; k += 2) {
      float2 a = zg2[(size_t)adj[k] * 64];
      float2 b = zg2[(size_t)adj[k + 1] * 64];
      val.x += a.x + b.x;
      val.y += a.y + b.y;
    }
    if (k < b1) {
      float2 a = zg2[(size_t)adj[k] * 64];
      val.x += a.x; val.y += a.y;
    }
    S2[n * 64 + lane] = val;
  }
  __syncthreads();

  // gather + eout: o = relu(as*S[s] + ad*S[d] + az*z + bias)
  const float2 bb = ((const float2*)bias)[lane];
  for (int j = w; j < EG; j += NW) {
    int p = pke[j];
    int s = p & 255, d = (p >> 8) & 255;
    float a_s = as_[j], a_d = ad_[j], a_z = az_[j];
    float2 Sv = S2[s * 64 + lane];
    float2 Dv = S2[d * 64 + lane];
    float2 zv = zg2[(size_t)j * 64];
    float2 o;
    o.x = fmaxf(a_s * Sv.x + a_d * Dv.x + a_z * zv.x + bb.x, 0.f);
    o.y = fmaxf(a_s * Sv.y + a_d * Dv.y + a_z * zv.y + bb.y, 0.f);
    eo2[(size_t)j * 64] = o;
  }
}

// ---------- score dot: zs[i] = e[i] . wsc  (4 lanes per row) ----------
__global__ __launch_bounds__(256) void k_sdot(const float* __restrict__ e,
                                              const float* __restrict__ wsc,
                                              float* __restrict__ zs, int E) {
  int t = threadIdx.x, wv = t >> 6, lane = t & 63;
  int row = blockIdx.x * 64 + wv * 16 + (lane >> 2);
  int sub = lane & 3;
  if (row >= E) return;
  const float4* ep = (const float4*)(e + (size_t)row * 128) + sub;
  const float4* wp = (const float4*)wsc + sub;
  float s = 0.f;
#pragma unroll
  for (int k = 0; k < 8; ++k) {
    float4 a = ep[k * 4], b = wp[k * 4];
    s += a.x * b.x + a.y * b.y + a.z * b.z + a.w * b.w;
  }
  s += __shfl_xor(s, 1);
  s += __shfl_xor(s, 2);
  if (sub == 0) zs[row] = s;
}

// ---------- per-graph score finalize + top-k sort + compaction ----------
template <int EG, int KEEP, int ENEW>
__global__ __launch_bounds__(256) void k_sortcompact(const float* __restrict__ zs,
                                                     const int* __restrict__ ei_old, int E_old,
                                                     const float* __restrict__ bsc,
                                                     const float* __restrict__ e_old,
                                                     int* __restrict__ ei_new,
                                                     float* __restrict__ e_new,
                                                     float* __restrict__ ew) {
  __shared__ float ss[512];
  __shared__ int   si[512];
  __shared__ int   pke[512];
  __shared__ float Ssh[256], bcs[256];
  int g = blockIdx.x, t = threadIdx.x;
  if (t < 256) { Ssh[t] = 0.f; bcs[t] = 0.f; }
  __syncthreads();
  for (int j = t; j < EG; j += 256) {
    int s = ei_old[g * EG + j] & 255, d = ei_old[E_old + g * EG + j] & 255;
    pke[j] = s | (d << 8);
    atomicAdd(&bcs[s], 1.f);
    atomicAdd(&bcs[d], 1.f);
  }
  __syncthreads();
  for (int j = t; j < EG; j += 256) {
    float v = zs[g * EG + j];
    atomicAdd(&Ssh[pke[j] & 255], v);
    atomicAdd(&Ssh[(pke[j] >> 8) & 255], v);
  }
  __syncthreads();
  float bsc0 = bsc[0];
  for (int i = t; i < 512; i += 256) {
    if (i < EG) {
      int s = pke[i] & 255, d = (pke[i] >> 8) & 255;
      float bs = bcs[s], bd = bcs[d];
      float bis  = (bs != 1.f) ? 1.f / bs : 0.f;
      float bid_ = (bd != 1.f) ? 1.f / bd : 0.f;
      float dn = 1.f + (bs != 1.f ? 1.f : 0.f) + (bd != 1.f ? 1.f : 0.f);
      ss[i] = tanhf((Ssh[s] * bis + Ssh[d] * bid_ + zs[g * EG + i]) / dn + bsc0);
      si[i] = i;
    } else { ss[i] = -INFINITY; si[i] = 0x7FFFFFFF; }
  }
  __syncthreads();
  for (int k = 2; k <= 512; k <<= 1) {
    for (int j = k >> 1; j > 0; j >>= 1) {
      for (int i = t; i < 512; i += 256) {
        int ixj = i ^ j;
        if (ixj > i) {
          float s1 = ss[i], s2 = ss[ixj];
          int i1 = si[i], i2 = si[ixj];
          bool firstBetter = (s1 > s2) || (s1 == s2 && i1 < i2);
          bool desc = ((i & k) == 0);
          if (desc != firstBetter) {
            ss[i] = s2; si[i] = i2; ss[ixj] = s1; si[ixj] = i1;
          }
        }
      }
      __syncthreads();
    }
  }
  for (int j = t; j < KEEP; j += 256) {
    int oldp = g * EG + si[j];
    int newp = g * KEEP + j;
    ei_new[newp]        = ei_old[oldp];
    ei_new[ENEW + newp] = ei_old[E_old + oldp];
    ew[newp] = fminf(fmaxf(ss[j], 0.f), 1.f);
  }
  __syncthreads();
  for (int q = t; q < KEEP * 32; q += 256) {
    int j = q >> 5, c4 = (q & 31) << 2;
    *(float4*)&e_new[(size_t)(g * KEEP + j) * 128 + c4] =
        *(const float4*)&e_old[(size_t)(g * EG + si[j]) * 128 + c4];
  }
}

// ---------- final MLP ----------
__global__ __launch_bounds__(128) void k_mlp(const float* __restrict__ xs,
                                             const float* __restrict__ Wc1, const float* __restrict__ bc1,
                                             const float* __restrict__ Wc2, const float* __restrict__ bc2,
                                             const float* __restrict__ Wc3, const float* __restrict__ bc3,
                                             float* __restrict__ out) {
  __shared__ float row[384];
  __shared__ float h1[128];
  __shared__ float h2[64];
  int g = blockIdx.x, t = threadIdx.x;
  for (int i = t; i < 384; i += 128) row[i] = xs[g * 384 + i];
  __syncthreads();
  float a = bc1[t];
  for (int k = 0; k < 384; ++k) a += row[k] * Wc1[k * 128 + t];
  h1[t] = fmaxf(a, 0.f);
  __syncthreads();
  if (t < 64) {
    float b = bc2[t];
    for (int k = 0; k < 128; ++k) b += h1[k] * Wc2[k * 64 + t];
    h2[t] = fmaxf(b, 0.f);
  }
  __syncthreads();
  float o = bc3[t];
  for (int k = 0; k < 64; ++k) o += h2[k] * Wc3[k * 128 + t];
  out[g * 128 + t] = o;
}

extern "C" void kernel_launch(void* const* d_in, const int* in_sizes, int n_in,
                              void* d_out, int out_size, void* d_ws, size_t ws_size,
                              hipStream_t stream) {
  (void)in_sizes; (void)n_in; (void)out_size; (void)ws_size;
  const int*   x_idx  = (const int*)d_in[0];
  const int*   b_idx  = (const int*)d_in[1];
  const int*   ei0    = (const int*)d_in[2];
  const float* atom_t = (const float*)d_in[4];
  const float* bond_t = (const float*)d_in[5];
  const float* W_gcn  = (const float*)d_in[6];
  const float* b_gcn  = (const float*)d_in[7];
  const float* root   = (const float*)d_in[8];
  const float* W_hyp  = (const float*)d_in[9];
  const float* b_hyp  = (const float*)d_in[10];
  const float* W_sc   = (const float*)d_in[11];
  const float* b_sc   = (const float*)d_in[12];
  const float* Wc1    = (const float*)d_in[13];
  const float* bc1_   = (const float*)d_in[14];
  const float* Wc2    = (const float*)d_in[15];
  const float* bc2_   = (const float*)d_in[16];
  const float* Wc3    = (const float*)d_in[17];
  const float* bc3_   = (const float*)d_in[18];
  float* out = (float*)d_out;

  // workspace layout
  float* x    = (float*)d_ws;
  float* h    = x    + (size_t)NTOT * D;
  float* eA   = h    + (size_t)NTOT * D;
  float* eB   = eA   + (size_t)E0 * D;
  float* zs   = eB   + (size_t)E0 * D;
  float* ew   = zs   + E0;
  float* xs   = ew   + E0;
  int*   eiB  = (int*)(xs + BG * 384);
  int*   eiA2 = eiB + 2 * E0;

  hipMemsetAsync(xs, 0, BG * 384 * 4, stream);
  k_embed_x<<<NTOT * 32 / 256, 256, 0, stream>>>(x_idx, atom_t, x);
  k_embed_e<<<E0 * 32 / 256, 256, 0, stream>>>(b_idx, bond_t, eA);

  // ---- layer 0 ----
  k_gemm_bf16<<<NTOT / 128, 256, 0, stream>>>(x, W_gcn, b_gcn, h);
  k_gcn_fused<EG0, false><<<BG, 1024, 0, stream>>>(ei0, E0, eA, h, nullptr, root, x, xs);
  k_gemm_bf16<<<E0 / 128, 256, 0, stream>>>(eA, W_hyp, nullptr, eB);
  k_hyper_fused<EG0><<<BG, 1024, 0, stream>>>(ei0, E0, eB, b_hyp, eA);
  k_sdot<<<E0 / 64, 256, 0, stream>>>(eA, W_sc, zs, E0);
  k_sortcompact<EG0, KP0, E1><<<BG, 256, 0, stream>>>(zs, ei0, E0, b_sc, eA, eiB, eB, ew);

  // ---- layer 1 ----
  k_gemm_bf16<<<NTOT / 128, 256, 0, stream>>>(x, W_gcn + D * D, b_gcn + D, h);
  k_gcn_fused<KP0, true><<<BG, 1024, 0, stream>>>(eiB, E1, eB, h, ew, root + D, x, xs);
  k_gemm_bf16<<<E1 / 128, 256, 0, stream>>>(eB, W_hyp + D * D, nullptr, eA);
  k_hyper_fused<KP0><<<BG, 1024, 0, stream>>>(eiB, E1, eA, b_hyp + D, eB);
  k_sdot<<<E1 / 64, 256, 0, stream>>>(eB, W_sc + D, zs, E1);
  k_sortcompact<KP0, KP1, E2><<<BG, 256, 0, stream>>>(zs, eiB, E1, b_sc + 1, eB, eiA2, eA, ew);

  // ---- layer 2 ----
  k_gemm_bf16<<<NTOT / 128, 256, 0, stream>>>(x, W_gcn + 2 * D * D, b_gcn + 2 * D, h);
  k_gcn_fused<KP1, true><<<BG, 1024, 0, stream>>>(eiA2, E2, eA, h, ew, root + 2 * D, x, xs);

  k_mlp<<<BG, 128, 0, stream>>>(xs, Wc1, bc1_, Wc2, bc2_, Wc3, bc3_, out);
}

// Round 11
// 366.269 us; speedup vs baseline: 2.8024x; 1.1181x over previous
//
#include <hip/hip_runtime.h>
#include <hip/hip_bf16.h>
#include <math.h>

constexpr int NTOT = 65536;
constexpr int D    = 128;
constexpr int BG   = 256;
constexpr int E0 = 131072, E1 = 104960, E2 = 83968;
constexpr int EG0 = 512;
constexpr int KP0 = 410, KP1 = 328;

typedef __bf16 bf16x8 __attribute__((ext_vector_type(8)));
typedef float  f32x4  __attribute__((ext_vector_type(4)));

// ---------- embeddings ----------
__global__ __launch_bounds__(256) void k_embed_x(const int* __restrict__ xi,
                                                 const float* __restrict__ tab,
                                                 float* __restrict__ x) {
  int t = blockIdx.x * 256 + threadIdx.x;      // NTOT*32 threads
  int v = t >> 5, q = (t & 31) << 2;
  float4 s = {0.f, 0.f, 0.f, 0.f};
#pragma unroll
  for (int j = 0; j < 9; ++j) {
    int r = xi[v * 9 + j];
    float4 a = *(const float4*)&tab[r * D + q];
    s.x += a.x; s.y += a.y; s.z += a.z; s.w += a.w;
  }
  *(float4*)&x[v * D + q] = s;
}

__global__ __launch_bounds__(256) void k_embed_e(const int* __restrict__ bi,
                                                 const float* __restrict__ tab,
                                                 float* __restrict__ e) {
  int t = blockIdx.x * 256 + threadIdx.x;      // E0*32 threads
  int i = t >> 5, q = (t & 31) << 2;
  float4 s = {0.f, 0.f, 0.f, 0.f};
#pragma unroll
  for (int j = 0; j < 3; ++j) {
    int r = bi[i * 3 + j];
    float4 a = *(const float4*)&tab[r * D + q];
    s.x += a.x; s.y += a.y; s.z += a.z; s.w += a.w;
  }
  *(float4*)&e[i * D + q] = s;
}

// ---------- bf16 MFMA GEMM: C[M][128] = A[M][128] @ W[128][128] (+bias) ----------
__global__ __launch_bounds__(256) void k_gemm_bf16(const float* __restrict__ A,
                                                   const float* __restrict__ W,
                                                   const float* __restrict__ bias,
                                                   float* __restrict__ C) {
  __shared__ bf16x8 Wl[4][8][64];              // [ks][nt][lane] fragments, 32 KB
  const int t = threadIdx.x, w = t >> 6, lane = t & 63;
  const int m0 = blockIdx.x * 128;

  bf16x8* Wf = (bf16x8*)Wl;
  for (int q = t; q < 2048; q += 256) {
    int ks = q >> 9, nt = (q >> 6) & 7, l = q & 63;
    int kk = ks * 32 + ((l >> 4) << 3);
    int nn = nt * 16 + (l & 15);
    const float* wp = W + (size_t)kk * 128 + nn;
    bf16x8 v;
#pragma unroll
    for (int b = 0; b < 8; ++b) v[b] = (__bf16)wp[(size_t)b * 128];
    Wf[q] = v;
  }

  const int r0 = m0 + w * 32 + (lane & 15);
  const float* Ap0 = A + (size_t)r0 * 128 + ((lane >> 4) << 3);
  const float* Ap1 = Ap0 + 16 * 128;
  bf16x8 a0[4], a1[4];
#pragma unroll
  for (int ks = 0; ks < 4; ++ks) {
    float4 x0 = *(const float4*)(Ap0 + ks * 32);
    float4 x1 = *(const float4*)(Ap0 + ks * 32 + 4);
    float4 y0 = *(const float4*)(Ap1 + ks * 32);
    float4 y1 = *(const float4*)(Ap1 + ks * 32 + 4);
    bf16x8 u, v;
    u[0] = (__bf16)x0.x; u[1] = (__bf16)x0.y; u[2] = (__bf16)x0.z; u[3] = (__bf16)x0.w;
    u[4] = (__bf16)x1.x; u[5] = (__bf16)x1.y; u[6] = (__bf16)x1.z; u[7] = (__bf16)x1.w;
    v[0] = (__bf16)y0.x; v[1] = (__bf16)y0.y; v[2] = (__bf16)y0.z; v[3] = (__bf16)y0.w;
    v[4] = (__bf16)y1.x; v[5] = (__bf16)y1.y; v[6] = (__bf16)y1.z; v[7] = (__bf16)y1.w;
    a0[ks] = u; a1[ks] = v;
  }
  __syncthreads();

  f32x4 acc0[8] = {}; f32x4 acc1[8] = {};
#pragma unroll
  for (int ks = 0; ks < 4; ++ks) {
#pragma unroll
    for (int nt = 0; nt < 8; ++nt) {
      bf16x8 b = Wl[ks][nt][lane];
      acc0[nt] = __builtin_amdgcn_mfma_f32_16x16x32_bf16(a0[ks], b, acc0[nt], 0, 0, 0);
      acc1[nt] = __builtin_amdgcn_mfma_f32_16x16x32_bf16(a1[ks], b, acc1[nt], 0, 0, 0);
    }
  }

  const int orow = m0 + w * 32 + ((lane >> 4) << 2);
  const int ocol = lane & 15;
#pragma unroll
  for (int nt = 0; nt < 8; ++nt) {
    float bb = bias ? bias[nt * 16 + ocol] : 0.f;
    float* cp = C + (size_t)orow * 128 + nt * 16 + ocol;
#pragma unroll
    for (int r = 0; r < 4; ++r) {
      cp[(size_t)r * 128]        = acc0[nt][r] + bb;
      cp[(size_t)(16 + r) * 128] = acc1[nt][r] + bb;
    }
  }
}

// ---------- fused GCN layer: 1 block/graph, 1024 thr, full 128 cols (float2/lane).
//            CSR-grouped, per-edge coef precomputed in LDS. ----------
template <int EG, bool HAS_EW>
__global__ __launch_bounds__(1024, 4) void k_gcn_fused(const int* __restrict__ ei, int E,
                                                       const float* __restrict__ e,
                                                       const float* __restrict__ h,
                                                       const float* __restrict__ ew,
                                                       const float* __restrict__ root,
                                                       float* __restrict__ x,
                                                       float* __restrict__ xs) {
  constexpr int NW = 16;
  __shared__ float acc[256 * 128];            // 128 KB
  __shared__ int   pke[EG];
  __shared__ float coef[EG];
  __shared__ int   cnts[256];
  __shared__ int   cntd[256];
  __shared__ int   off[257];
  __shared__ int   cur[256];
  __shared__ short adj[EG];
  __shared__ float redm[1024], reds[1024];
  const int g = blockIdx.x;
  const int t = threadIdx.x, w = t >> 6, lane = t & 63;
  const float2* eg2 = (const float2*)e + (size_t)g * EG * 64 + lane;
  const float2* hg2 = (const float2*)h + (size_t)g * 256 * 64 + lane;
  float2* acc2 = (float2*)acc;

  if (t < 256) { cnts[t] = 0; cntd[t] = 0; }
  __syncthreads();

  for (int j = t; j < EG; j += 1024) {
    int s = ei[g * EG + j] & 255, d = ei[E + g * EG + j] & 255;
    pke[j] = s | (d << 8);
    atomicAdd(&cnts[s], 1);
    atomicAdd(&cntd[d], 1);
  }
  __syncthreads();

  // per-edge coefficient (both endpoints folded in)
  for (int j = t; j < EG; j += 1024) {
    int p = pke[j];
    int s = p & 255, d = (p >> 8) & 255;
    float c = rsqrtf(((float)cnts[s] + 1.f) * ((float)cnts[d] + 1.f));
    if (HAS_EW) c *= ew[g * EG + j];
    coef[j] = c;
  }

  // exclusive scan of cntd
  if (t < 256) off[t + 1] = cntd[t];
  if (t == 0) off[0] = 0;
  __syncthreads();
  for (int st = 1; st < 256; st <<= 1) {
    int add = 0;
    if (t < 256 && t + 1 > st) add = off[t + 1 - st];
    __syncthreads();
    if (t < 256) off[t + 1] += add;
    __syncthreads();
  }
  if (t < 256) cur[t] = off[t];
  __syncthreads();

  for (int j = t; j < EG; j += 1024) {
    int d = (pke[j] >> 8) & 255;
    int pos = atomicAdd(&cur[d], 1);
    adj[pos] = (short)j;
  }
  __syncthreads();

  // accumulate per dst node (float2, plain writes)
  for (int n = w; n < 256; n += NW) {
    float2 val = {0.f, 0.f};
    int b0 = off[n], b1 = off[n + 1];
    int k = b0;
    for (; k + 1 < b1; k += 2) {
      int j0 = adj[k], j1 = adj[k + 1];
      int s0 = pke[j0] & 255, s1 = pke[j1] & 255;
      float2 e0 = eg2[(size_t)j0 * 64], e1 = eg2[(size_t)j1 * 64];
      float2 h0 = hg2[(size_t)s0 * 64], h1 = hg2[(size_t)s1 * 64];
      float c0 = coef[j0], c1 = coef[j1];
      val.x += c0 * fmaxf(h0.x + e0.x, 0.f) + c1 * fmaxf(h1.x + e1.x, 0.f);
      val.y += c0 * fmaxf(h0.y + e0.y, 0.f) + c1 * fmaxf(h1.y + e1.y, 0.f);
    }
    if (k < b1) {
      int j0 = adj[k];
      int s0 = pke[j0] & 255;
      float2 e0 = eg2[(size_t)j0 * 64];
      float2 h0 = hg2[(size_t)s0 * 64];
      float c0 = coef[j0];
      val.x += c0 * fmaxf(h0.x + e0.x, 0.f);
      val.y += c0 * fmaxf(h0.y + e0.y, 0.f);
    }
    acc2[n * 64 + lane] = val;
  }
  __syncthreads();

  // finalize: x = relu(acc + relu(h+root)/deg); keep in LDS for readout
  float4* a4 = (float4*)acc;
  for (int i = t; i < 8192; i += 1024) {
    int n = i >> 5, q = (i & 31) << 2;
    float inv = 1.f / ((float)cnts[n] + 1.f);
    size_t gi = (size_t)(g * 256 + n) * 128 + q;
    float4 hv = *(const float4*)&h[gi];
    float4 rv = *(const float4*)&root[q];
    float4 av = a4[i];
    float4 xv;
    xv.x = fmaxf(av.x + fmaxf(hv.x + rv.x, 0.f) * inv, 0.f);
    xv.y = fmaxf(av.y + fmaxf(hv.y + rv.y, 0.f) * inv, 0.f);
    xv.z = fmaxf(av.z + fmaxf(hv.z + rv.z, 0.f) * inv, 0.f);
    xv.w = fmaxf(av.w + fmaxf(hv.w + rv.w, 0.f) * inv, 0.f);
    *(float4*)&x[gi] = xv;
    a4[i] = xv;
  }
  __syncthreads();

  // readout: 8 partials per column (t = r*128 + c)
  {
    int c = t & 127, r = t >> 7;
    float mx = -1e30f, sm = 0.f;
    for (int n = r; n < 256; n += 8) {
      float v = acc[n * 128 + c];
      mx = fmaxf(mx, v); sm += v;
    }
    redm[t] = mx; reds[t] = sm;
  }
  __syncthreads();
  if (t < 128) {
    float M = redm[t], S2 = reds[t];
#pragma unroll
    for (int k = 1; k < 8; ++k) {
      M = fmaxf(M, redm[k * 128 + t]);
      S2 += reds[k * 128 + t];
    }
    xs[g * 384 + t]       += M;
    xs[g * 384 + 128 + t] += S2 * (1.f / 256.f);
    xs[g * 384 + 256 + t] += S2;
  }
}

// ---------- fused hyperconv: 1 block/graph, 1024 thr, full cols (float2/lane).
//            CSR incidence accumulation + gather + eout + fused score dot. ----------
template <int EG>
__global__ __launch_bounds__(1024, 4) void k_hyper_fused(const int* __restrict__ ei, int E,
                                                         const float* __restrict__ z,
                                                         const float* __restrict__ bias,
                                                         const float* __restrict__ wsc,
                                                         float* __restrict__ eout,
                                                         float* __restrict__ zs) {
  constexpr int NW = 16;
  __shared__ float S[256 * 128];              // 128 KB
  __shared__ int   pke[EG];
  __shared__ float as_[EG], ad_[EG], az_[EG];
  __shared__ int   cnt[256];
  __shared__ int   off[257];
  __shared__ int   cur[256];
  __shared__ short adj[2 * EG];
  const int g = blockIdx.x;
  const int t = threadIdx.x, w = t >> 6, lane = t & 63;
  const float2* zg2 = (const float2*)z + (size_t)g * EG * 64 + lane;
  float2* eo2 = (float2*)eout + (size_t)g * EG * 64 + lane;
  float2* S2 = (float2*)S;

  if (t < 256) cnt[t] = 0;
  __syncthreads();

  for (int j = t; j < EG; j += 1024) {
    int s = ei[g * EG + j] & 255, d = ei[E + g * EG + j] & 255;
    pke[j] = s | (d << 8);
    atomicAdd(&cnt[s], 1);
    atomicAdd(&cnt[d], 1);
  }
  __syncthreads();

  // per-edge gather constants
  for (int j = t; j < EG; j += 1024) {
    int p = pke[j];
    int s = p & 255, d = (p >> 8) & 255;
    int cs = cnt[s], cd = cnt[d];
    float bis  = (cs != 1) ? 1.f / (float)cs : 0.f;
    float bid_ = (cd != 1) ? 1.f / (float)cd : 0.f;
    float dinv = 1.f / (1.f + (cs != 1 ? 1.f : 0.f) + (cd != 1 ? 1.f : 0.f));
    as_[j] = dinv * bis;
    ad_[j] = dinv * bid_;
    az_[j] = dinv;
  }

  if (t < 256) off[t + 1] = cnt[t];
  if (t == 0) off[0] = 0;
  __syncthreads();
  for (int st = 1; st < 256; st <<= 1) {
    int add = 0;
    if (t < 256 && t + 1 > st) add = off[t + 1 - st];
    __syncthreads();
    if (t < 256) off[t + 1] += add;
    __syncthreads();
  }
  if (t < 256) cur[t] = off[t];
  __syncthreads();

  for (int j = t; j < EG; j += 1024) {
    int p = pke[j];
    int pos0 = atomicAdd(&cur[p & 255], 1);
    adj[pos0] = (short)j;
    int pos1 = atomicAdd(&cur[(p >> 8) & 255], 1);
    adj[pos1] = (short)j;
  }
  __syncthreads();

  // accumulate per node (float2, plain writes)
  for (int n = w; n < 256; n += NW) {
    float2 val = {0.f, 0.f};
    int b0 = off[n], b1 = off[n + 1];
    int k = b0;
    for (; k + 1 < b1; k += 2) {
      float2 a = zg2[(size_t)adj[k] * 64];
      float2 b = zg2[(size_t)adj[k + 1] * 64];
      val.x += a.x + b.x;
      val.y += a.y + b.y;
    }
    if (k < b1) {
      float2 a = zg2[(size_t)adj[k] * 64];
      val.x += a.x; val.y += a.y;
    }
    S2[n * 64 + lane] = val;
  }
  __syncthreads();

  // gather + eout + fused score dot: o = relu(as*S[s] + ad*S[d] + az*z + bias)
  const float2 bb = ((const float2*)bias)[lane];
  const float2 w2 = ((const float2*)wsc)[lane];
  for (int j = w; j < EG; j += NW) {
    int p = pke[j];
    int s = p & 255, d = (p >> 8) & 255;
    float a_s = as_[j], a_d = ad_[j], a_z = az_[j];
    float2 Sv = S2[s * 64 + lane];
    float2 Dv = S2[d * 64 + lane];
    float2 zv = zg2[(size_t)j * 64];
    float2 o;
    o.x = fmaxf(a_s * Sv.x + a_d * Dv.x + a_z * zv.x + bb.x, 0.f);
    o.y = fmaxf(a_s * Sv.y + a_d * Dv.y + a_z * zv.y + bb.y, 0.f);
    eo2[(size_t)j * 64] = o;
    float part = o.x * w2.x + o.y * w2.y;
#pragma unroll
    for (int offs = 32; offs > 0; offs >>= 1) part += __shfl_xor(part, offs);
    if (lane == 0) zs[g * EG + j] = part;
  }
}

// ---------- per-graph score finalize + register-bitonic top-k + compaction.
//            512 threads, 1 element/thread; shuffles for stride<64. ----------
template <int EG, int KEEP, int ENEW>
__global__ __launch_bounds__(512) void k_sortcompact(const float* __restrict__ zs,
                                                     const int* __restrict__ ei_old, int E_old,
                                                     const float* __restrict__ bsc,
                                                     const float* __restrict__ e_old,
                                                     int* __restrict__ ei_new,
                                                     float* __restrict__ e_new,
                                                     float* __restrict__ ew) {
  __shared__ float ls[512];
  __shared__ int   li[512];
  __shared__ int   pke[512];
  __shared__ float Ssh[256], bcs[256];
  __shared__ int   sidx[512];
  const int g = blockIdx.x, t = threadIdx.x;
  if (t < 256) { Ssh[t] = 0.f; bcs[t] = 0.f; }
  __syncthreads();
  if (t < EG) {
    int s = ei_old[g * EG + t] & 255, d = ei_old[E_old + g * EG + t] & 255;
    pke[t] = s | (d << 8);
    atomicAdd(&bcs[s], 1.f);
    atomicAdd(&bcs[d], 1.f);
  }
  __syncthreads();
  if (t < EG) {
    float v = zs[g * EG + t];
    atomicAdd(&Ssh[pke[t] & 255], v);
    atomicAdd(&Ssh[(pke[t] >> 8) & 255], v);
  }
  __syncthreads();
  float s; int idx;
  if (t < EG) {
    int p = pke[t];
    int sn = p & 255, dn = (p >> 8) & 255;
    float bs = bcs[sn], bd = bcs[dn];
    float bis  = (bs != 1.f) ? 1.f / bs : 0.f;
    float bid_ = (bd != 1.f) ? 1.f / bd : 0.f;
    float dnm = 1.f + (bs != 1.f ? 1.f : 0.f) + (bd != 1.f ? 1.f : 0.f);
    s = tanhf((Ssh[sn] * bis + Ssh[dn] * bid_ + zs[g * EG + t]) / dnm + bsc[0]);
    idx = t;
  } else { s = -INFINITY; idx = 0x7FFFFFFF; }

  // bitonic sort, descending by (score, then idx asc). stride<64 via shuffles.
#pragma unroll
  for (int k = 2; k <= 512; k <<= 1) {
#pragma unroll
    for (int j = k >> 1; j > 0; j >>= 1) {
      float ps; int pi;
      if (j < 64) {
        ps = __shfl_xor(s, j);
        pi = __shfl_xor(idx, j);
      } else {
        ls[t] = s; li[t] = idx;
        __syncthreads();
        ps = ls[t ^ j]; pi = li[t ^ j];
        __syncthreads();
      }
      bool ownBetter = (s > ps) || (s == ps && idx < pi);
      bool lower = ((t & j) == 0);
      bool desc = ((t & k) == 0);
      bool keep = desc ? (lower ? ownBetter : !ownBetter)
                       : (lower ? !ownBetter : ownBetter);
      if (!keep) { s = ps; idx = pi; }
    }
  }

  sidx[t] = idx;
  if (t < KEEP) {
    int oldp = g * EG + idx;
    int newp = g * KEEP + t;
    ei_new[newp]        = ei_old[oldp];
    ei_new[ENEW + newp] = ei_old[E_old + oldp];
    ew[newp] = fminf(fmaxf(s, 0.f), 1.f);
  }
  __syncthreads();
  for (int q = t; q < KEEP * 32; q += 512) {
    int j2 = q >> 5, c4 = (q & 31) << 2;
    *(float4*)&e_new[(size_t)(g * KEEP + j2) * 128 + c4] =
        *(const float4*)&e_old[(size_t)(g * EG + sidx[j2]) * 128 + c4];
  }
}

// ---------- final MLP ----------
__global__ __launch_bounds__(128) void k_mlp(const float* __restrict__ xs,
                                             const float* __restrict__ Wc1, const float* __restrict__ bc1,
                                             const float* __restrict__ Wc2, const float* __restrict__ bc2,
                                             const float* __restrict__ Wc3, const float* __restrict__ bc3,
                                             float* __restrict__ out) {
  __shared__ float row[384];
  __shared__ float h1[128];
  __shared__ float h2[64];
  int g = blockIdx.x, t = threadIdx.x;
  for (int i = t; i < 384; i += 128) row[i] = xs[g * 384 + i];
  __syncthreads();
  float a = bc1[t];
  for (int k = 0; k < 384; ++k) a += row[k] * Wc1[k * 128 + t];
  h1[t] = fmaxf(a, 0.f);
  __syncthreads();
  if (t < 64) {
    float b = bc2[t];
    for (int k = 0; k < 128; ++k) b += h1[k] * Wc2[k * 64 + t];
    h2[t] = fmaxf(b, 0.f);
  }
  __syncthreads();
  float o = bc3[t];
  for (int k = 0; k < 64; ++k) o += h2[k] * Wc3[k * 128 + t];
  out[g * 128 + t] = o;
}

extern "C" void kernel_launch(void* const* d_in, const int* in_sizes, int n_in,
                              void* d_out, int out_size, void* d_ws, size_t ws_size,
                              hipStream_t stream) {
  (void)in_sizes; (void)n_in; (void)out_size; (void)ws_size;
  const int*   x_idx  = (const int*)d_in[0];
  const int*   b_idx  = (const int*)d_in[1];
  const int*   ei0    = (const int*)d_in[2];
  const float* atom_t = (const float*)d_in[4];
  const float* bond_t = (const float*)d_in[5];
  const float* W_gcn  = (const float*)d_in[6];
  const float* b_gcn  = (const float*)d_in[7];
  const float* root   = (const float*)d_in[8];
  const float* W_hyp  = (const float*)d_in[9];
  const float* b_hyp  = (const float*)d_in[10];
  const float* W_sc   = (const float*)d_in[11];
  const float* b_sc   = (const float*)d_in[12];
  const float* Wc1    = (const float*)d_in[13];
  const float* bc1_   = (const float*)d_in[14];
  const float* Wc2    = (const float*)d_in[15];
  const float* bc2_   = (const float*)d_in[16];
  const float* Wc3    = (const float*)d_in[17];
  const float* bc3_   = (const float*)d_in[18];
  float* out = (float*)d_out;

  // workspace layout
  float* x    = (float*)d_ws;
  float* h    = x    + (size_t)NTOT * D;
  float* eA   = h    + (size_t)NTOT * D;
  float* eB   = eA   + (size_t)E0 * D;
  float* zs   = eB   + (size_t)E0 * D;
  float* ew   = zs   + E0;
  float* xs   = ew   + E0;
  int*   eiB  = (int*)(xs + BG * 384);
  int*   eiA2 = eiB + 2 * E0;

  hipMemsetAsync(xs, 0, BG * 384 * 4, stream);
  k_embed_x<<<NTOT * 32 / 256, 256, 0, stream>>>(x_idx, atom_t, x);
  k_embed_e<<<E0 * 32 / 256, 256, 0, stream>>>(b_idx, bond_t, eA);

  // ---- layer 0 ----
  k_gemm_bf16<<<NTOT / 128, 256, 0, stream>>>(x, W_gcn, b_gcn, h);
  k_gcn_fused<EG0, false><<<BG, 1024, 0, stream>>>(ei0, E0, eA, h, nullptr, root, x, xs);
  k_gemm_bf16<<<E0 / 128, 256, 0, stream>>>(eA, W_hyp, nullptr, eB);
  k_hyper_fused<EG0><<<BG, 1024, 0, stream>>>(ei0, E0, eB, b_hyp, W_sc, eA, zs);
  k_sortcompact<EG0, KP0, E1><<<BG, 512, 0, stream>>>(zs, ei0, E0, b_sc, eA, eiB, eB, ew);

  // ---- layer 1 ----
  k_gemm_bf16<<<NTOT / 128, 256, 0, stream>>>(x, W_gcn + D * D, b_gcn + D, h);
  k_gcn_fused<KP0, true><<<BG, 1024, 0, stream>>>(eiB, E1, eB, h, ew, root + D, x, xs);
  k_gemm_bf16<<<E1 / 128, 256, 0, stream>>>(eB, W_hyp + D * D, nullptr, eA);
  k_hyper_fused<KP0><<<BG, 1024, 0, stream>>>(eiB, E1, eA, b_hyp + D, W_sc + D, eB, zs);
  k_sortcompact<KP0, KP1, E2><<<BG, 512, 0, stream>>>(zs, eiB, E1, b_sc + 1, eB, eiA2, eA, ew);

  // ---- layer 2 ----
  k_gemm_bf16<<<NTOT / 128, 256, 0, stream>>>(x, W_gcn + 2 * D * D, b_gcn + 2 * D, h);
  k_gcn_fused<KP1, true><<<BG, 1024, 0, stream>>>(eiA2, E2, eA, h, ew, root + 2 * D, x, xs);

  k_mlp<<<BG, 128, 0, stream>>>(xs, Wc1, bc1_, Wc2, bc2_, Wc3, bc3_, out);
}